// Round 10
// baseline (1056.830 us; speedup 1.0000x reference)
//
#include <hip/hip_runtime.h>
#include <hip/hip_bf16.h>

#define T_TOK 8192
#define DIM   1024
#define A4D   4096
#define HDIM  2048
#define NE    6
#define MB    ((size_t)1 << 20)
#define MELT  1048576L   // elements in a 1024x1024 matrix

typedef __attribute__((ext_vector_type(4))) float f32x4;
typedef __attribute__((ext_vector_type(8))) short bf16x8;
typedef __attribute__((ext_vector_type(4))) short s16x4;

__device__ __forceinline__ float bf2f(short b){
  union { unsigned u; float f; } c; c.u = ((unsigned)(unsigned short)b) << 16; return c.f;
}
__device__ __forceinline__ short f2bf(float f){
  union { float f; unsigned u; } c; c.f = f;
  unsigned u = c.u;
  unsigned r = (u + 0x7fffu + ((u >> 16) & 1u)) >> 16;
  return (short)r;
}

__device__ __forceinline__ void gl_lds16(const short* g, short* l){
  __builtin_amdgcn_global_load_lds(
      (const __attribute__((address_space(1))) void*)g,
      (__attribute__((address_space(3))) void*)l, 16, 0, 0);
}

template<int N> __device__ __forceinline__ void wait_vmcnt(){
  if constexpr (N >= 8)      asm volatile("s_waitcnt vmcnt(8)" ::: "memory");
  else if constexpr (N == 6) asm volatile("s_waitcnt vmcnt(6)" ::: "memory");
  else if constexpr (N == 4) asm volatile("s_waitcnt vmcnt(4)" ::: "memory");
  else if constexpr (N == 2) asm volatile("s_waitcnt vmcnt(2)" ::: "memory");
  else                       asm volatile("s_waitcnt vmcnt(0)" ::: "memory");
}

// ---------------------------------------------------------------- GEMM ----
// C[M,N] = A[M,K](bf16,row-major) @ B (given as BT[N,K] bf16 row-major)
// mode 0: simple (z-batched via strides)
// mode 1: expert gather-A (A rows via toklist, M = ecount[z])
// mode 2: expert contiguous-A (A += ebase[z]*lda, M = ecount[z])
// mode 3: expm pairs: A = A + (z&3)*sA; BT = (z<4 ? BT : BT2) + (z&3)*sBT
struct GemmArgs {
  const short* A; const short* BT; const short* BT2;
  long sA, sBT;
  short* Cb; short* CbT; float* Racc;
  long sCb, sCbT, sR;
  const float* bias; long sBias;
  const float* rowscale;
  const int* toklist; const int* ebase; const int* ecount;
  float alpha;
  int M, N, K, lda, ldb, ldc, ldcbt;
  int mode, do_gelu;
};

// ===== 128-class kernel: 256 threads, 4 waves (2x2), depth-3 counted vmcnt.
// Proven at R5 (845us). Used for the expm path.
template<int MF, int NF>
__global__ __launch_bounds__(256)
void gemm_kernel(GemmArgs g){
  constexpr int BM = 32*MF, BN = 32*NF;
  constexpr int CA = (BM*32)/2048;
  constexpr int CB = (BN*32)/2048;
  constexpr int PS = CA + CB;
  const int z  = blockIdx.z;

  int bx = blockIdx.x, by = blockIdx.y;
  {
    int gx = gridDim.x, gy = gridDim.y;
    if ((gy & 7) == 0){
      int linear = by*gx + bx;
      int per = gx << 3;
      int grp = linear / per, rem = linear % per;
      bx = rem >> 3;
      by = (grp << 3) + (rem & 7);
    }
  }
  const int m0 = by * BM;
  const int n0 = bx * BN;

  const short* A; const short* BT;
  if (g.mode == 3){
    A  = g.A + (long)(z & 3) * g.sA;
    BT = ((z < 4) ? g.BT : g.BT2) + (long)(z & 3) * g.sBT;
  } else {
    A  = g.A  + (long)z * g.sA;
    BT = g.BT + (long)z * g.sBT;
  }

  __shared__ __align__(16) short As[3][BM*32];
  __shared__ __align__(16) short Bs[3][BN*32];

  const int tid  = threadIdx.x;
  const int wid  = tid >> 6;
  const int lane = tid & 63;
  const int wr = wid >> 1, wc = wid & 1;
  const int lrow = lane & 15, lgrp = lane >> 4;

  const short* aP[CA]; const short* bP[CB];
  int aDoff[CA], bDoff[CB];
  #pragma unroll
  for (int c = 0; c < CA; ++c){
    int q = c*256 + tid;
    int r = q >> 2;
    int colel = ((q & 3) ^ ((r >> 1) & 3)) * 8;
    aP[c] = A + (long)(m0 + r) * g.lda + colel;
    aDoff[c] = (c*256 + wid*64) * 8;
  }
  #pragma unroll
  for (int c = 0; c < CB; ++c){
    int q = c*256 + tid;
    int r = q >> 2;
    int colel = ((q & 3) ^ ((r >> 1) & 3)) * 8;
    bP[c] = BT + (long)(n0 + r) * g.ldb + colel;
    bDoff[c] = (c*256 + wid*64) * 8;
  }

  f32x4 acc[MF][NF];
  #pragma unroll
  for (int i = 0; i < MF; ++i)
    #pragma unroll
    for (int j = 0; j < NF; ++j) acc[i][j] = (f32x4){0.f,0.f,0.f,0.f};

  int aRoff[MF], bRoff[NF];
  #pragma unroll
  for (int mi = 0; mi < MF; ++mi){
    int R = wr*(16*MF) + mi*16 + lrow;
    aRoff[mi] = R*32 + ((lgrp ^ ((R >> 1) & 3)) * 8);
  }
  #pragma unroll
  for (int ni = 0; ni < NF; ++ni){
    int R = wc*(16*NF) + ni*16 + lrow;
    bRoff[ni] = R*32 + ((lgrp ^ ((R >> 1) & 3)) * 8);
  }

  auto stage = [&](int buf, int ko){
    #pragma unroll
    for (int c = 0; c < CA; ++c) gl_lds16(aP[c] + ko, &As[buf][aDoff[c]]);
    #pragma unroll
    for (int c = 0; c < CB; ++c) gl_lds16(bP[c] + ko, &Bs[buf][bDoff[c]]);
  };

  const int nk = g.K / 32;   // must be >= 3
  stage(0, 0); stage(1, 32); stage(2, 64);
  int buf = 0;
  for (int t = 0; t < nk; ++t){
    if (t < nk-2)       wait_vmcnt<2*PS>();
    else if (t == nk-2) wait_vmcnt<PS>();
    else                wait_vmcnt<0>();
    asm volatile("s_barrier" ::: "memory");
    bf16x8 af[MF], bfr[NF];
    #pragma unroll
    for (int mi = 0; mi < MF; ++mi)
      af[mi] = *(const bf16x8*)&As[buf][aRoff[mi]];
    #pragma unroll
    for (int ni = 0; ni < NF; ++ni)
      bfr[ni] = *(const bf16x8*)&Bs[buf][bRoff[ni]];
    asm volatile("s_waitcnt lgkmcnt(0)" ::: "memory");
    asm volatile("s_barrier" ::: "memory");
    if (t + 3 < nk) stage(buf, (t + 3) * 32);
    #pragma unroll
    for (int mi = 0; mi < MF; ++mi)
      #pragma unroll
      for (int ni = 0; ni < NF; ++ni)
        acc[mi][ni] = __builtin_amdgcn_mfma_f32_16x16x32_bf16(af[mi], bfr[ni], acc[mi][ni], 0, 0, 0);
    buf = (buf == 2) ? 0 : buf + 1;
  }

  #pragma unroll
  for (int mi = 0; mi < MF; ++mi){
    #pragma unroll
    for (int ni = 0; ni < NF; ++ni){
      int gc = n0 + wc*(16*NF) + ni*16 + lrow;
      #pragma unroll
      for (int j = 0; j < 4; ++j){
        int gr = m0 + wr*(16*MF) + mi*16 + lgrp*4 + j;
        float v = acc[mi][ni][j] * g.alpha;
        if (g.Racc) g.Racc[(long)z*g.sR + (long)gr*g.ldc + gc] += v;
        if (g.Cb)   g.Cb[(long)z*g.sCb + (long)gr*g.ldc + gc] = f2bf(v);
        if (g.CbT)  g.CbT[(long)z*g.sCbT + (long)gc*g.ldcbt + gr] = f2bf(v);
      }
    }
  }
}

// ===== tri-buffered phased kernel: 512 threads, 8 waves (4M x 2N), BK=64,
// tile 256x128, per-wave 64x64 (acc[4][4] - proven profile). 3 K-tile LDS
// buffers (144KB); iter u stages tile u+2 split across 4 phases; counted
// vmcnt(6) at iter top (tile u's 6 loads are the oldest -> guaranteed
// landed; tile u+1's stay in flight). ONE barrier per iter. Modes 0/1/2.
__global__ __launch_bounds__(512)
void gemm_tri(GemmArgs g){
  constexpr int BM = 256, BN = 128;
  constexpr int CA = 4, CB = 2, CT = 6;
  const int z = blockIdx.z;

  int bx = blockIdx.x, by = blockIdx.y;
  {
    int gx = gridDim.x, gy = gridDim.y;
    if ((gy & 7) == 0){
      int linear = by*gx + bx;
      int per = gx << 3;
      int grp = linear / per, rem = linear % per;
      bx = rem >> 3;
      by = (grp << 3) + (rem & 7);
    }
  }
  const int m0 = by * BM;
  const int n0 = bx * BN;

  const short* A; const short* BT;
  const int* rows = nullptr;
  int M = g.M;
  int rowbase = 0;
  if (g.mode == 0){
    A  = g.A  + (long)z * g.sA;
    BT = g.BT + (long)z * g.sBT;
  } else {
    int cnt = g.ecount[z];
    if (m0 >= cnt) return;
    M = cnt;
    rowbase = g.ebase[z];
    BT = g.BT + (long)z * g.sBT;
    if (g.mode == 1){ A = g.A; rows = g.toklist + rowbase; }
    else            { A = g.A + (long)rowbase * g.lda; }
  }

  __shared__ __align__(16) short As[3][BM*64];   // 96 KB
  __shared__ __align__(16) short Bs[3][BN*64];   // 48 KB

  const int tid  = threadIdx.x;
  const int wid  = tid >> 6;
  const int lane = tid & 63;
  const int wr = wid >> 1, wc = wid & 1;         // 4M x 2N wave grid
  const int lrow = lane & 15, lgrp = lane >> 4;

  // staging sources: calls 0..3 cover A rows c*64..c*64+63; 4..5 cover B.
  const short* gP[CT]; int dOffA[CA], dOffB[CB];
  #pragma unroll
  for (int c = 0; c < CT; ++c){
    int rl = (c < CA ? c : c - CA)*64 + (tid >> 3);
    int colel = ((tid & 7) ^ (rl & 7)) * 8;      // source chunk swizzle
    if (c < CA){
      long arow;
      if (g.mode == 1){
        int rr = m0 + rl; if (rr > M-1) rr = M-1;
        arow = rows[rr];
      } else if (g.mode == 2){
        int rr = m0 + rl; if (rr > M-1) rr = M-1;
        arow = rr;
      } else {
        arow = m0 + rl;
      }
      gP[c] = A + arow * (long)g.lda + colel;
      dOffA[c] = c*4096 + tid*8;
    } else {
      gP[c] = BT + (long)(n0 + rl) * g.ldb + colel;
      dOffB[c-CA] = (c-CA)*4096 + tid*8;
    }
  }

  auto stage_call = [&](int buf, int c, int ko){
    if (c < CA) gl_lds16(gP[c] + ko, &As[buf][dOffA[c]]);
    else        gl_lds16(gP[c] + ko, &Bs[buf][dOffB[c-CA]]);
  };

  f32x4 acc[4][4];
  #pragma unroll
  for (int i = 0; i < 4; ++i)
    #pragma unroll
    for (int j = 0; j < 4; ++j) acc[i][j] = (f32x4){0.f,0.f,0.f,0.f};

  int aBase[4], bBase[4], csw[2];
  #pragma unroll
  for (int mi = 0; mi < 4; ++mi) aBase[mi] = (wr*64 + mi*16 + lrow)*64;
  #pragma unroll
  for (int ni = 0; ni < 4; ++ni) bBase[ni] = (wc*64 + ni*16 + lrow)*64;
  #pragma unroll
  for (int ks = 0; ks < 2; ++ks) csw[ks] = (((ks<<2) | lgrp) ^ (lrow & 7)) * 8;

  const int nk = g.K / 64;   // >= 3 for all uses (min K=1024 -> 16)
  #pragma unroll
  for (int c = 0; c < CT; ++c) stage_call(0, c, 0);
  #pragma unroll
  for (int c = 0; c < CT; ++c) stage_call(1, c, 64);

  int bufR = 0;
  for (int u = 0; u < nk; ++u){
    if (u < nk-1) wait_vmcnt<CT>();   // tile u landed; tile u+1 in flight
    else          wait_vmcnt<0>();    // tail: ensure last tile landed
    asm volatile("s_barrier" ::: "memory");
    const int bufW = (bufR == 0) ? 2 : bufR - 1;  // (u+2)%3
    const bool pf = (u + 2 < nk);
    const int ko = (u + 2) * 64;
    // B fragments for the whole tile (8 reads)
    bf16x8 bfr[4][2];
    #pragma unroll
    for (int ni = 0; ni < 4; ++ni)
      #pragma unroll
      for (int ks = 0; ks < 2; ++ks)
        bfr[ni][ks] = *(const bf16x8*)&Bs[bufR][bBase[ni] + csw[ks]];
    // 4 phases: stage-share | af reads | MFMA burst
    #pragma unroll
    for (int q = 0; q < 4; ++q){
      if (pf){
        if (q == 0){ stage_call(bufW, 0, ko); stage_call(bufW, 1, ko); }
        else if (q == 1){ stage_call(bufW, 2, ko); stage_call(bufW, 3, ko); }
        else if (q == 2){ stage_call(bufW, 4, ko); }
        else            { stage_call(bufW, 5, ko); }
      }
      bf16x8 af[2];
      #pragma unroll
      for (int ks = 0; ks < 2; ++ks)
        af[ks] = *(const bf16x8*)&As[bufR][aBase[q] + csw[ks]];
      __builtin_amdgcn_s_setprio(1);
      #pragma unroll
      for (int ni = 0; ni < 4; ++ni)
        #pragma unroll
        for (int ks = 0; ks < 2; ++ks)
          acc[q][ni] = __builtin_amdgcn_mfma_f32_16x16x32_bf16(
              af[ks], bfr[ni][ks], acc[q][ni], 0, 0, 0);
      __builtin_amdgcn_s_setprio(0);
    }
    bufR = (bufR == 2) ? 0 : bufR + 1;
  }

  #pragma unroll
  for (int mi = 0; mi < 4; ++mi){
    #pragma unroll
    for (int ni = 0; ni < 4; ++ni){
      int gc = n0 + wc*64 + ni*16 + lrow;
      #pragma unroll
      for (int j = 0; j < 4; ++j){
        int gr = m0 + wr*64 + mi*16 + lgrp*4 + j;
        if ((g.mode == 1 || g.mode == 2) && gr >= M) continue;
        float v = acc[mi][ni][j] * g.alpha;
        if (g.bias)     v += g.bias[(long)z*g.sBias + gc];
        if (g.rowscale) v *= g.rowscale[rowbase + gr];
        if (g.do_gelu)  v = 0.5f*v*(1.0f + erff(v*0.70710678118654752f));
        long ro = (long)rowbase + gr;
        if (g.Cb) g.Cb[(long)z*g.sCb + ro*(long)g.ldc + gc] = f2bf(v);
      }
    }
  }
}

// ------------------------------------------------------- transpose conv ----
__global__ __launch_bounds__(256)
void transpose_f32_to_bf16(const float* src, short* dst, int R, int C, long sSrc, long sDst){
  __shared__ float tile[32][33];
  const float* S = src + (long)blockIdx.z * sSrc;
  short* D = dst + (long)blockIdx.z * sDst;
  int c0 = blockIdx.x*32, r0 = blockIdx.y*32;
  int tx = threadIdx.x & 31;
  int ty = threadIdx.x >> 5;
  #pragma unroll
  for (int j = 0; j < 32; j += 8)
    tile[ty+j][tx] = S[(long)(r0+ty+j)*C + (c0+tx)];
  __syncthreads();
  #pragma unroll
  for (int j = 0; j < 32; j += 8)
    D[(long)(c0+ty+j)*R + (r0+tx)] = f2bf(tile[tx][ty+j]);
}

__global__ void f32_to_bf16_kernel(const float* src, short* dst){
  int i = blockIdx.x*256 + threadIdx.x;
  dst[i] = f2bf(src[i]);
}

// Racc = I + G + G2/2 + G3/6 + G4/24 ; Sb = bf16(G/120 + G2/720 + G3/5040 + G4/40320)
__global__ void poly_kernel(const float* gens, const short* G2b, const short* G34b,
                            float* Racc, short* Sb){
  int i = blockIdx.x*256 + threadIdx.x;
  float g  = gens[i];
  float g2 = bf2f(G2b[i]);
  float g3 = bf2f(G34b[i]);
  float g4 = bf2f(G34b[4*MELT + i]);
  int w = i & (int)(MELT-1);
  float id = ((w >> 10) == (w & 1023)) ? 1.0f : 0.0f;
  Racc[i] = id + g + 0.5f*g2 + (1.0f/6.0f)*g3 + (1.0f/24.0f)*g4;
  Sb[i] = f2bf((1.0f/120.0f)*g + (1.0f/720.0f)*g2 + (1.0f/5040.0f)*g3 + (1.0f/40320.0f)*g4);
}

// -------------------------------------------- LayerNorm + routing fused ----
__global__ __launch_bounds__(256)
void ln_route_kernel(const float* x, const float* g, const float* b,
                     const float* gate_w, const float* gate_b, short* xnb,
                     int* e0a, int* e1a, float* w0a, float* w1a){
  int row = blockIdx.x;
  const float* xr = x + (long)row*DIM;
  f32x4 v = ((const f32x4*)xr)[threadIdx.x];
  float s1 = v[0]+v[1]+v[2]+v[3];
  float s2 = v[0]*v[0]+v[1]*v[1]+v[2]*v[2]+v[3]*v[3];
  #pragma unroll
  for (int o = 32; o; o >>= 1){ s1 += __shfl_xor(s1,o); s2 += __shfl_xor(s2,o); }
  __shared__ float p1[4], p2[4], pl[4][NE];
  int w = threadIdx.x >> 6, l = threadIdx.x & 63;
  if (l == 0){ p1[w] = s1; p2[w] = s2; }
  __syncthreads();
  float mu = (p1[0]+p1[1]+p1[2]+p1[3]) * (1.0f/DIM);
  float ms = (p2[0]+p2[1]+p2[2]+p2[3]) * (1.0f/DIM);
  float rs = rsqrtf(ms - mu*mu + 1e-5f);
  f32x4 gv = ((const f32x4*)g)[threadIdx.x];
  f32x4 bv = ((const f32x4*)b)[threadIdx.x];
  s16x4 ob;
  float lg[NE] = {0.f,0.f,0.f,0.f,0.f,0.f};
  #pragma unroll
  for (int j = 0; j < 4; ++j){
    float t = (v[j]-mu)*rs*gv[j] + bv[j];
    ob[j] = f2bf(t);
    const float* gwr = gate_w + (threadIdx.x*4 + j)*NE;
    #pragma unroll
    for (int e = 0; e < NE; ++e) lg[e] += t * gwr[e];
  }
  ((s16x4*)(xnb + (long)row*DIM))[threadIdx.x] = ob;
  #pragma unroll
  for (int o = 32; o; o >>= 1)
    #pragma unroll
    for (int e = 0; e < NE; ++e) lg[e] += __shfl_xor(lg[e], o);
  if (l == 0)
    #pragma unroll
    for (int e = 0; e < NE; ++e) pl[w][e] = lg[e];
  __syncthreads();
  if (threadIdx.x == 0){
    float s[NE];
    #pragma unroll
    for (int e = 0; e < NE; ++e) s[e] = pl[0][e]+pl[1][e]+pl[2][e]+pl[3][e] + gate_b[e];
    int b0 = 0;
    #pragma unroll
    for (int e = 1; e < NE; ++e) if (s[e] > s[b0]) b0 = e;
    int b1 = -1;
    #pragma unroll
    for (int e = 0; e < NE; ++e){ if (e == b0) continue; if (b1 < 0 || s[e] > s[b1]) b1 = e; }
    float ex = expf(s[b1] - s[b0]);
    float inv = 1.0f/(1.0f + ex);
    e0a[row] = b0; e1a[row] = b1; w0a[row] = inv; w1a[row] = ex*inv;
  }
}

// ---- routing compaction: LDS histogram -> serial prefix -> LDS-cursor scatter
__global__ __launch_bounds__(256)
void hist_kernel(const int* e0, const int* e1, int* blockhist){
  __shared__ int h[NE];
  if (threadIdx.x < NE) h[threadIdx.x] = 0;
  __syncthreads();
  int t = blockIdx.x*256 + threadIdx.x;
  atomicAdd(&h[e0[t]], 1);
  atomicAdd(&h[e1[t]], 1);
  __syncthreads();
  if (threadIdx.x < NE) blockhist[blockIdx.x*NE + threadIdx.x] = h[threadIdx.x];
}

#define NBLK_R (T_TOK/256)
__global__ void prefix2_kernel(const int* blockhist, int* ebase, int* counts, int* blockoff){
  if (threadIdx.x == 0){
    int tot[NE];
    for (int e = 0; e < NE; ++e) tot[e] = 0;
    for (int b = 0; b < NBLK_R; ++b)
      for (int e = 0; e < NE; ++e) tot[e] += blockhist[b*NE + e];
    int base = 0;
    int run[NE];
    for (int e = 0; e < NE; ++e){ ebase[e] = base; counts[e] = tot[e]; run[e] = base; base += tot[e]; }
    for (int b = 0; b < NBLK_R; ++b)
      for (int e = 0; e < NE; ++e){ blockoff[b*NE + e] = run[e]; run[e] += blockhist[b*NE + e]; }
  }
}

__global__ __launch_bounds__(256)
void scatter2_kernel(const int* e0, const int* e1, const float* w0, const float* w1,
                     const int* blockoff, int* ctok, float* cw, int* t2r){
  __shared__ int off[NE];
  if (threadIdx.x < NE) off[threadIdx.x] = blockoff[blockIdx.x*NE + threadIdx.x];
  __syncthreads();
  int t = blockIdx.x*256 + threadIdx.x;
  int a = e0[t], b = e1[t];
  int r0 = atomicAdd(&off[a], 1);
  ctok[r0] = t; cw[r0] = w0[t]; t2r[2*t] = r0;
  int r1 = atomicAdd(&off[b], 1);
  ctok[r1] = t; cw[r1] = w1[t]; t2r[2*t+1] = r1;
}

// nonabel[t] = eo[r0] + eo[r1]
__global__ __launch_bounds__(256)
void combine_kernel(const short* eo, const int* t2r, short* nonab){
  int t = blockIdx.x;
  int r0 = t2r[t*2], r1 = t2r[t*2+1];
  s16x4 a = ((const s16x4*)(eo + (long)r0*DIM))[threadIdx.x];
  s16x4 b = ((const s16x4*)(eo + (long)r1*DIM))[threadIdx.x];
  s16x4 o;
  #pragma unroll
  for (int j = 0; j < 4; ++j) o[j] = f2bf(bf2f(a[j]) + bf2f(b[j]));
  ((s16x4*)(nonab + (long)t*DIM))[threadIdx.x] = o;
}

// out = x + abel*(1-g) + rot*g ;  g = sigmoid([abel,rot] @ gc_w + gc_b)
__global__ __launch_bounds__(256)
void final_kernel(const float* x, const short* abel, const short* rot,
                  const float* gcw, const float* gcb, float* out){
  int t = blockIdx.x;
  f32x4 xv = ((const f32x4*)(x + (long)t*DIM))[threadIdx.x];
  s16x4 av = ((const s16x4*)(abel + (long)t*DIM))[threadIdx.x];
  s16x4 rv = ((const s16x4*)(rot  + (long)t*DIM))[threadIdx.x];
  f32x4 ga = ((const f32x4*)gcw)[threadIdx.x];
  f32x4 gr = ((const f32x4*)(gcw + DIM))[threadIdx.x];
  float af[4], rf[4];
  float s = 0.f;
  #pragma unroll
  for (int j = 0; j < 4; ++j){
    af[j] = bf2f(av[j]); rf[j] = bf2f(rv[j]);
    s += af[j]*ga[j] + rf[j]*gr[j];
  }
  #pragma unroll
  for (int o = 32; o; o >>= 1) s += __shfl_xor(s, o);
  __shared__ float p[4];
  int w = threadIdx.x >> 6, l = threadIdx.x & 63;
  if (l == 0) p[w] = s;
  __syncthreads();
  float tot = p[0]+p[1]+p[2]+p[3] + gcb[0];
  float gate = 1.0f/(1.0f + expf(-tot));
  f32x4 o;
  #pragma unroll
  for (int j = 0; j < 4; ++j) o[j] = xv[j] + af[j]*(1.0f-gate) + rf[j]*gate;
  ((f32x4*)(out + (long)t*DIM))[threadIdx.x] = o;
}

// ---------------------------------------------------------------- host ----
extern "C" void kernel_launch(void* const* d_in, const int* in_sizes, int n_in,
                              void* d_out, int out_size, void* d_ws, size_t ws_size,
                              hipStream_t stream){
  const float* x      = (const float*)d_in[0];
  const float* ln_g   = (const float*)d_in[1];
  const float* ln_b   = (const float*)d_in[2];
  const float* aw1    = (const float*)d_in[3];
  const float* ab1    = (const float*)d_in[4];
  const float* aw2    = (const float*)d_in[5];
  const float* ab2    = (const float*)d_in[6];
  const float* gate_w = (const float*)d_in[7];
  const float* gate_b = (const float*)d_in[8];
  const float* ew1    = (const float*)d_in[9];
  const float* eb1    = (const float*)d_in[10];
  const float* ew2    = (const float*)d_in[11];
  const float* eb2    = (const float*)d_in[12];
  const float* gens   = (const float*)d_in[13];
  const float* gc_w   = (const float*)d_in[14];
  const float* gc_b   = (const float*)d_in[15];
  float* out = (float*)d_out;
  (void)in_sizes; (void)n_in; (void)out_size; (void)ws_size;

  char* ws = (char*)d_ws;
  // expm scratch
  short* Gb    = (short*)(ws +   0*MB);
  short* GbT   = (short*)(ws +   8*MB);
  short* G2b   = (short*)(ws +  16*MB);
  short* G2bT  = (short*)(ws +  24*MB);
  short* G34b  = (short*)(ws +  32*MB);
  short* G34bT = (short*)(ws +  48*MB);
  float* Racc  = (float*)(ws +  64*MB);
  short* Sb    = (short*)(ws +  80*MB);
  short* Rb    = (short*)(ws +  88*MB);
  short* RbT   = (short*)(ws +  96*MB);
  short* Mpair = (short*)(ws + 104*MB);
  short* MpairT= (short*)(ws + 106*MB);
  // weights / activations
  short* aw1bT = (short*)(ws +   0*MB);
  short* aw2bT = (short*)(ws +   8*MB);
  short* ew1bT = (short*)(ws +  16*MB);
  short* ew2bT = (short*)(ws +  40*MB);
  short* xn_bf = (short*)(ws +  64*MB);
  short* rot   = (short*)(ws +  64*MB);
  short* hsh   = (short*)(ws +  80*MB);
  short* nonab = (short*)(ws +  80*MB);
  short* abel  = (short*)(ws + 144*MB);
  short* eo    = (short*)(ws + 160*MB);
  short* MbT   = (short*)(ws + 192*MB);
  // small
  int*   counts   = (int*)  (ws + 194*MB);
  int*   ebase    = (int*)  (ws + 194*MB + 1024);
  int*   blockhist= (int*)  (ws + 194*MB + 2048);
  int*   blockoff = (int*)  (ws + 194*MB + 4096);
  int*   e0a   = (int*)  (ws + 194*MB +  64*1024);
  int*   e1a   = (int*)  (ws + 194*MB +  96*1024);
  float* w0a   = (float*)(ws + 194*MB + 128*1024);
  float* w1a   = (float*)(ws + 194*MB + 160*1024);
  int*   ctok  = (int*)  (ws + 194*MB + 192*1024);
  float* cw    = (float*)(ws + 194*MB + 256*1024);
  int*   t2r   = (int*)  (ws + 194*MB + 320*1024);

  // ---- stage a: M = expm(g0)expm(g1)expm(g2)expm(g3), order-8 Taylor
  transpose_f32_to_bf16<<<dim3(32, 32, 4), 256, 0, stream>>>(gens, GbT, DIM, DIM, MELT, MELT);
  f32_to_bf16_kernel<<<4*MELT/256, 256, 0, stream>>>(gens, Gb);
  { // G2 = G*G (z=4), keep row-major + transposed
    GemmArgs ga{}; ga.A = Gb; ga.BT = GbT; ga.sA = MELT; ga.sBT = MELT;
    ga.Cb = G2b; ga.sCb = MELT; ga.CbT = G2bT; ga.sCbT = MELT; ga.ldcbt = DIM;
    ga.alpha = 1.f;
    ga.M = DIM; ga.N = DIM; ga.K = DIM; ga.lda = DIM; ga.ldb = DIM; ga.ldc = DIM;
    gemm_kernel<2,2><<<dim3(16, 16, 4), 256, 0, stream>>>(ga);
  }
  { // z=0..3: G3 = G2*G ; z=4..7: G4 = G2*G2
    GemmArgs ga{}; ga.mode = 3; ga.A = G2b; ga.BT = GbT; ga.BT2 = G2bT;
    ga.sA = MELT; ga.sBT = MELT;
    ga.Cb = G34b; ga.sCb = MELT; ga.CbT = G34bT; ga.sCbT = MELT; ga.ldcbt = DIM;
    ga.alpha = 1.f;
    ga.M = DIM; ga.N = DIM; ga.K = DIM; ga.lda = DIM; ga.ldb = DIM; ga.ldc = DIM;
    gemm_kernel<2,2><<<dim3(16, 16, 8), 256, 0, stream>>>(ga);
  }
  poly_kernel<<<4*MELT/256, 256, 0, stream>>>(gens, G2b, G34b, Racc, Sb);
  { // Racc += S*G4  (powers commute: supplies Taylor terms 5..8)
    GemmArgs ga{}; ga.A = Sb; ga.BT = G34bT + 4*MELT; ga.sA = MELT; ga.sBT = MELT;
    ga.Racc = Racc; ga.sR = MELT; ga.alpha = 1.f;
    ga.M = DIM; ga.N = DIM; ga.K = DIM; ga.lda = DIM; ga.ldb = DIM; ga.ldc = DIM;
    gemm_kernel<2,2><<<dim3(16, 16, 4), 256, 0, stream>>>(ga);
  }
  f32_to_bf16_kernel<<<4*MELT/256, 256, 0, stream>>>(Racc, Rb);
  transpose_f32_to_bf16<<<dim3(32, 32, 3), 256, 0, stream>>>(Racc + MELT, RbT, DIM, DIM, MELT, MELT);
  { // z=0: M01 = R0*R1 ; z=1: M23 = R2*R3
    GemmArgs ga{}; ga.A = Rb; ga.BT = RbT; ga.sA = 2*MELT; ga.sBT = 2*MELT;
    ga.Cb = Mpair; ga.sCb = MELT; ga.CbT = MpairT; ga.sCbT = MELT; ga.ldcbt = DIM;
    ga.alpha = 1.f;
    ga.M = DIM; ga.N = DIM; ga.K = DIM; ga.lda = DIM; ga.ldb = DIM; ga.ldc = DIM;
    gemm_kernel<2,2><<<dim3(16, 16, 2), 256, 0, stream>>>(ga);
  }
  { // M = M01*M23, stored transposed
    GemmArgs ga{}; ga.A = Mpair; ga.BT = MpairT + MELT;
    ga.CbT = MbT; ga.ldcbt = DIM; ga.alpha = 1.f;
    ga.M = DIM; ga.N = DIM; ga.K = DIM; ga.lda = DIM; ga.ldb = DIM; ga.ldc = DIM;
    gemm_kernel<2,2><<<dim3(16, 16, 1), 256, 0, stream>>>(ga);
  }

  // ---- stage b: weight conversions (f32 -> bf16 [N,K])
  transpose_f32_to_bf16<<<dim3(A4D/32, DIM/32, 1), 256, 0, stream>>>(aw1, aw1bT, DIM, A4D, 0, 0);
  transpose_f32_to_bf16<<<dim3(DIM/32, A4D/32, 1), 256, 0, stream>>>(aw2, aw2bT, A4D, DIM, 0, 0);
  transpose_f32_to_bf16<<<dim3(HDIM/32, DIM/32, NE), 256, 0, stream>>>(ew1, ew1bT, DIM, HDIM, (long)DIM*HDIM, (long)DIM*HDIM);
  transpose_f32_to_bf16<<<dim3(DIM/32, HDIM/32, NE), 256, 0, stream>>>(ew2, ew2bT, HDIM, DIM, (long)DIM*HDIM, (long)DIM*HDIM);

  // ---- stage c: LayerNorm + routing, atomic-free compaction
  ln_route_kernel<<<T_TOK, 256, 0, stream>>>(x, ln_g, ln_b, gate_w, gate_b,
                                             xn_bf, e0a, e1a, w0a, w1a);
  hist_kernel<<<NBLK_R, 256, 0, stream>>>(e0a, e1a, blockhist);
  prefix2_kernel<<<1, 64, 0, stream>>>(blockhist, ebase, counts, blockoff);
  scatter2_kernel<<<NBLK_R, 256, 0, stream>>>(e0a, e1a, w0a, w1a, blockoff, ctok, cw, t2r);

  // ---- stage d: abel branch
  {
    GemmArgs ga{}; ga.A = xn_bf; ga.BT = aw1bT; ga.Cb = hsh;
    ga.bias = ab1; ga.alpha = 1.f; ga.do_gelu = 1;
    ga.M = T_TOK; ga.N = A4D; ga.K = DIM; ga.lda = DIM; ga.ldb = DIM; ga.ldc = A4D;
    gemm_tri<<<dim3(A4D/128, T_TOK/256, 1), 512, 0, stream>>>(ga);
  }
  {
    GemmArgs ga{}; ga.A = hsh; ga.BT = aw2bT; ga.Cb = abel;
    ga.bias = ab2; ga.alpha = 1.f;
    ga.M = T_TOK; ga.N = DIM; ga.K = A4D; ga.lda = A4D; ga.ldb = A4D; ga.ldc = DIM;
    gemm_tri<<<dim3(DIM/128, T_TOK/256, 1), 512, 0, stream>>>(ga);
  }

  // ---- experts (gathered top-2)
  {
    GemmArgs ga{}; ga.mode = 1; ga.A = xn_bf; ga.BT = ew1bT; ga.sBT = (long)HDIM*DIM;
    ga.Cb = hsh; ga.bias = eb1; ga.sBias = HDIM; ga.alpha = 1.f; ga.do_gelu = 1;
    ga.toklist = ctok; ga.ebase = ebase; ga.ecount = counts;
    ga.M = T_TOK; ga.N = HDIM; ga.K = DIM; ga.lda = DIM; ga.ldb = DIM; ga.ldc = HDIM;
    gemm_tri<<<dim3(HDIM/128, T_TOK/256, NE), 512, 0, stream>>>(ga);
  }
  {
    GemmArgs ga{}; ga.mode = 2; ga.A = hsh; ga.BT = ew2bT; ga.sBT = (long)DIM*HDIM;
    ga.Cb = eo; ga.bias = eb2; ga.sBias = DIM; ga.rowscale = cw; ga.alpha = 1.f;
    ga.ebase = ebase; ga.ecount = counts;
    ga.M = T_TOK; ga.N = DIM; ga.K = HDIM; ga.lda = HDIM; ga.ldb = HDIM; ga.ldc = DIM;
    gemm_tri<<<dim3(DIM/128, T_TOK/256, NE), 512, 0, stream>>>(ga);
  }
  combine_kernel<<<T_TOK, 256, 0, stream>>>(eo, t2r, nonab);

  // ---- rot = nonabel @ M
  {
    GemmArgs ga{}; ga.A = nonab; ga.BT = MbT; ga.Cb = rot; ga.alpha = 1.f;
    ga.M = T_TOK; ga.N = DIM; ga.K = DIM; ga.lda = DIM; ga.ldb = DIM; ga.ldc = DIM;
    gemm_tri<<<dim3(DIM/128, T_TOK/256, 1), 512, 0, stream>>>(ga);
  }

  final_kernel<<<T_TOK, 256, 0, stream>>>(x, abel, rot, gc_w, gc_b, out);
}

// Round 11
// 791.831 us; speedup vs baseline: 1.3347x; 1.3347x over previous
//
#include <hip/hip_runtime.h>
#include <hip/hip_bf16.h>

#define T_TOK 8192
#define DIM   1024
#define A4D   4096
#define HDIM  2048
#define NE    6
#define MB    ((size_t)1 << 20)
#define MELT  1048576L   // elements in a 1024x1024 matrix

typedef __attribute__((ext_vector_type(4))) float f32x4;
typedef __attribute__((ext_vector_type(8))) short bf16x8;
typedef __attribute__((ext_vector_type(4))) short s16x4;

__device__ __forceinline__ float bf2f(short b){
  union { unsigned u; float f; } c; c.u = ((unsigned)(unsigned short)b) << 16; return c.f;
}
__device__ __forceinline__ short f2bf(float f){
  union { float f; unsigned u; } c; c.f = f;
  unsigned u = c.u;
  unsigned r = (u + 0x7fffu + ((u >> 16) & 1u)) >> 16;
  return (short)r;
}

__device__ __forceinline__ void gl_lds16(const short* g, short* l){
  __builtin_amdgcn_global_load_lds(
      (const __attribute__((address_space(1))) void*)g,
      (__attribute__((address_space(3))) void*)l, 16, 0, 0);
}

template<int N> __device__ __forceinline__ void wait_vmcnt(){
  if constexpr (N >= 8)      asm volatile("s_waitcnt vmcnt(8)" ::: "memory");
  else if constexpr (N == 4) asm volatile("s_waitcnt vmcnt(4)" ::: "memory");
  else if constexpr (N == 2) asm volatile("s_waitcnt vmcnt(2)" ::: "memory");
  else                       asm volatile("s_waitcnt vmcnt(0)" ::: "memory");
}

// ---------------------------------------------------------------- GEMM ----
// C[M,N] = A[M,K](bf16,row-major) @ B (given as BT[N,K] bf16 row-major)
// mode 0: simple (z-batched via strides)
// mode 1: expert gather-A (A rows via toklist, M = ecount[z])
// mode 2: expert contiguous-A (A += ebase[z]*lda, M = ecount[z])
struct GemmArgs {
  const short* A; const short* BT; const short* BT2;
  long sA, sBT;
  short* Cb; short* CbT; float* Racc;
  long sCb, sCbT, sR;
  const float* bias; long sBias;
  const float* rowscale;
  const int* toklist; const int* ebase; const int* ecount;
  float alpha;
  int M, N, K, lda, ldb, ldc, ldcbt;
  int mode, do_gelu;
};

// ===== 128-class kernel: 256 threads, 4 waves (2x2), depth-3 counted vmcnt.
// Proven at R5/R8. Used for expm path and all N=1024 GEMMs.
template<int MF, int NF>
__global__ __launch_bounds__(256)
void gemm_kernel(GemmArgs g){
  constexpr int BM = 32*MF, BN = 32*NF;
  constexpr int CA = (BM*32)/2048;
  constexpr int CB = (BN*32)/2048;
  constexpr int PS = CA + CB;
  const int z  = blockIdx.z;

  int bx = blockIdx.x, by = blockIdx.y;
  {
    int gx = gridDim.x, gy = gridDim.y;
    if ((gy & 7) == 0){
      int linear = by*gx + bx;
      int per = gx << 3;
      int grp = linear / per, rem = linear % per;
      bx = rem >> 3;
      by = (grp << 3) + (rem & 7);
    }
  }
  const int m0 = by * BM;
  const int n0 = bx * BN;

  const short* A; const short* BT;
  const int* rows = nullptr;
  int M = g.M;
  int rowbase = 0;
  if (g.mode == 0){
    A  = g.A  + (long)z * g.sA;
    BT = g.BT + (long)z * g.sBT;
  } else {
    int cnt = g.ecount[z];
    if (m0 >= cnt) return;
    M = cnt;
    rowbase = g.ebase[z];
    BT = g.BT + (long)z * g.sBT;
    if (g.mode == 1){ A = g.A; rows = g.toklist + rowbase; }
    else            { A = g.A + (long)rowbase * g.lda; }
  }

  __shared__ __align__(16) short As[3][BM*32];
  __shared__ __align__(16) short Bs[3][BN*32];

  const int tid  = threadIdx.x;
  const int wid  = tid >> 6;
  const int lane = tid & 63;
  const int wr = wid >> 1, wc = wid & 1;
  const int lrow = lane & 15, lgrp = lane >> 4;

  const short* aP[CA]; const short* bP[CB];
  int aDoff[CA], bDoff[CB];
  #pragma unroll
  for (int c = 0; c < CA; ++c){
    int q = c*256 + tid;
    int r = q >> 2;
    int colel = ((q & 3) ^ ((r >> 1) & 3)) * 8;
    long arow;
    if (g.mode == 1){
      int rr = m0 + r; if (rr > M-1) rr = M-1;
      arow = rows[rr];
    } else if (g.mode == 2){
      int rr = m0 + r; if (rr > M-1) rr = M-1;
      arow = rr;
    } else {
      arow = m0 + r;
    }
    aP[c] = A + arow * (long)g.lda + colel;
    aDoff[c] = (c*256 + wid*64) * 8;
  }
  #pragma unroll
  for (int c = 0; c < CB; ++c){
    int q = c*256 + tid;
    int r = q >> 2;
    int colel = ((q & 3) ^ ((r >> 1) & 3)) * 8;
    bP[c] = BT + (long)(n0 + r) * g.ldb + colel;
    bDoff[c] = (c*256 + wid*64) * 8;
  }

  f32x4 acc[MF][NF];
  #pragma unroll
  for (int i = 0; i < MF; ++i)
    #pragma unroll
    for (int j = 0; j < NF; ++j) acc[i][j] = (f32x4){0.f,0.f,0.f,0.f};

  int aRoff[MF], bRoff[NF];
  #pragma unroll
  for (int mi = 0; mi < MF; ++mi){
    int R = wr*(16*MF) + mi*16 + lrow;
    aRoff[mi] = R*32 + ((lgrp ^ ((R >> 1) & 3)) * 8);
  }
  #pragma unroll
  for (int ni = 0; ni < NF; ++ni){
    int R = wc*(16*NF) + ni*16 + lrow;
    bRoff[ni] = R*32 + ((lgrp ^ ((R >> 1) & 3)) * 8);
  }

  auto stage = [&](int buf, int ko){
    #pragma unroll
    for (int c = 0; c < CA; ++c) gl_lds16(aP[c] + ko, &As[buf][aDoff[c]]);
    #pragma unroll
    for (int c = 0; c < CB; ++c) gl_lds16(bP[c] + ko, &Bs[buf][bDoff[c]]);
  };

  const int nk = g.K / 32;   // must be >= 3
  stage(0, 0); stage(1, 32); stage(2, 64);
  int buf = 0;
  for (int t = 0; t < nk; ++t){
    if (t < nk-2)       wait_vmcnt<2*PS>();
    else if (t == nk-2) wait_vmcnt<PS>();
    else                wait_vmcnt<0>();
    asm volatile("s_barrier" ::: "memory");
    bf16x8 af[MF], bfr[NF];
    #pragma unroll
    for (int mi = 0; mi < MF; ++mi)
      af[mi] = *(const bf16x8*)&As[buf][aRoff[mi]];
    #pragma unroll
    for (int ni = 0; ni < NF; ++ni)
      bfr[ni] = *(const bf16x8*)&Bs[buf][bRoff[ni]];
    asm volatile("s_waitcnt lgkmcnt(0)" ::: "memory");
    asm volatile("s_barrier" ::: "memory");
    if (t + 3 < nk) stage(buf, (t + 3) * 32);
    #pragma unroll
    for (int mi = 0; mi < MF; ++mi)
      #pragma unroll
      for (int ni = 0; ni < NF; ++ni)
        acc[mi][ni] = __builtin_amdgcn_mfma_f32_16x16x32_bf16(af[mi], bfr[ni], acc[mi][ni], 0, 0, 0);
    buf = (buf == 2) ? 0 : buf + 1;
  }

  #pragma unroll
  for (int mi = 0; mi < MF; ++mi){
    #pragma unroll
    for (int ni = 0; ni < NF; ++ni){
      int gc = n0 + wc*(16*NF) + ni*16 + lrow;
      #pragma unroll
      for (int j = 0; j < 4; ++j){
        int gr = m0 + wr*(16*MF) + mi*16 + lgrp*4 + j;
        if ((g.mode == 1 || g.mode == 2) && gr >= M) continue;
        float v = acc[mi][ni][j] * g.alpha;
        if (g.bias)     v += g.bias[(long)z*g.sBias + gc];
        if (g.rowscale) v *= g.rowscale[rowbase + gr];
        if (g.do_gelu)  v = 0.5f*v*(1.0f + erff(v*0.70710678118654752f));
        long ro = (long)rowbase + gr;
        if (g.Racc) g.Racc[(long)z*g.sR + (long)gr*g.ldc + gc] += v;
        if (g.Cb)   g.Cb[(long)z*g.sCb + ro*(long)g.ldc + gc] = f2bf(v);
        if (g.CbT)  g.CbT[(long)z*g.sCbT + (long)gc*g.ldcbt + ro] = f2bf(v);
      }
    }
  }
}

// ===== 256-sq kernel: 1024 threads, 16 waves (4x4), per-wave 64x64 (acc[4][4]),
// BK=32, 64KB LDS, 2 blocks/CU. Proven at R8 (824us). Modes 0 and 1 only.
__global__ __launch_bounds__(1024)
void gemm_sq256(GemmArgs g){
  constexpr int BM = 256, BN = 256;
  const int z  = blockIdx.z;

  int bx = blockIdx.x, by = blockIdx.y;
  {
    int gx = gridDim.x, gy = gridDim.y;
    if ((gy & 7) == 0){
      int linear = by*gx + bx;
      int per = gx << 3;
      int grp = linear / per, rem = linear % per;
      bx = rem >> 3;
      by = (grp << 3) + (rem & 7);
    }
  }
  const int m0 = by * BM;
  const int n0 = bx * BN;

  const short* A; const short* BT;
  const int* rows = nullptr;
  int M = g.M;
  int rowbase = 0;
  if (g.mode == 0){
    A  = g.A  + (long)z * g.sA;
    BT = g.BT + (long)z * g.sBT;
  } else {
    int cnt = g.ecount[z];
    if (m0 >= cnt) return;
    M = cnt;
    rowbase = g.ebase[z];
    BT = g.BT + (long)z * g.sBT;
    A = g.A; rows = g.toklist + rowbase;   // mode 1
  }

  __shared__ __align__(16) short As[2][BM*32];
  __shared__ __align__(16) short Bs[2][BN*32];

  const int tid  = threadIdx.x;
  const int wid  = tid >> 6;         // 0..15
  const int lane = tid & 63;
  const int wr = wid >> 2, wc = wid & 3;   // 4x4 wave grid
  const int lrow = lane & 15, lgrp = lane >> 4;

  // staging: 1024 threads cover 256 rows x 32 cols (1 call each for A and B)
  const short* aP; const short* bP;
  int dOff;
  {
    int q = tid;
    int r = q >> 2;
    int colel = ((q & 3) ^ ((r >> 1) & 3)) * 8;
    long arow;
    if (g.mode == 1){
      int rr = m0 + r; if (rr > M-1) rr = M-1;
      arow = rows[rr];
    } else {
      arow = m0 + r;
    }
    aP = A + arow * (long)g.lda + colel;
    bP = BT + (long)(n0 + r) * g.ldb + colel;
    dOff = (wid*64) * 8;
  }

  f32x4 acc[4][4];
  #pragma unroll
  for (int i = 0; i < 4; ++i)
    #pragma unroll
    for (int j = 0; j < 4; ++j) acc[i][j] = (f32x4){0.f,0.f,0.f,0.f};

  int aRoff[4], bRoff[4];
  #pragma unroll
  for (int mi = 0; mi < 4; ++mi){
    int R = wr*64 + mi*16 + lrow;
    aRoff[mi] = R*32 + ((lgrp ^ ((R >> 1) & 3)) * 8);
  }
  #pragma unroll
  for (int ni = 0; ni < 4; ++ni){
    int R = wc*64 + ni*16 + lrow;
    bRoff[ni] = R*32 + ((lgrp ^ ((R >> 1) & 3)) * 8);
  }

  auto stage = [&](int buf, int ko){
    gl_lds16(aP + ko, &As[buf][dOff]);
    gl_lds16(bP + ko, &Bs[buf][dOff]);
  };

  const int nk = g.K / 32;
  stage(0, 0);
  __syncthreads();
  int buf = 0;
  for (int t = 0; t < nk; ++t){
    if (t + 1 < nk) stage(buf ^ 1, (t + 1) * 32);
    bf16x8 af[4], bfr[4];
    #pragma unroll
    for (int mi = 0; mi < 4; ++mi)
      af[mi] = *(const bf16x8*)&As[buf][aRoff[mi]];
    #pragma unroll
    for (int ni = 0; ni < 4; ++ni)
      bfr[ni] = *(const bf16x8*)&Bs[buf][bRoff[ni]];
    #pragma unroll
    for (int mi = 0; mi < 4; ++mi)
      #pragma unroll
      for (int ni = 0; ni < 4; ++ni)
        acc[mi][ni] = __builtin_amdgcn_mfma_f32_16x16x32_bf16(af[mi], bfr[ni], acc[mi][ni], 0, 0, 0);
    __syncthreads();
    buf ^= 1;
  }

  #pragma unroll
  for (int mi = 0; mi < 4; ++mi){
    #pragma unroll
    for (int ni = 0; ni < 4; ++ni){
      int gc = n0 + wc*64 + ni*16 + lrow;
      #pragma unroll
      for (int j = 0; j < 4; ++j){
        int gr = m0 + wr*64 + mi*16 + lgrp*4 + j;
        if (g.mode == 1 && gr >= M) continue;
        float v = acc[mi][ni][j] * g.alpha;
        if (g.bias)     v += g.bias[(long)z*g.sBias + gc];
        if (g.rowscale) v *= g.rowscale[rowbase + gr];
        if (g.do_gelu)  v = 0.5f*v*(1.0f + erff(v*0.70710678118654752f));
        long ro = (long)rowbase + gr;
        if (g.Cb) g.Cb[(long)z*g.sCb + ro*(long)g.ldc + gc] = f2bf(v);
      }
    }
  }
}

// ------------------------------------------------------- transpose conv ----
__global__ __launch_bounds__(256)
void transpose_f32_to_bf16(const float* src, short* dst, int R, int C, long sSrc, long sDst){
  __shared__ float tile[32][33];
  const float* S = src + (long)blockIdx.z * sSrc;
  short* D = dst + (long)blockIdx.z * sDst;
  int c0 = blockIdx.x*32, r0 = blockIdx.y*32;
  int tx = threadIdx.x & 31;
  int ty = threadIdx.x >> 5;
  #pragma unroll
  for (int j = 0; j < 32; j += 8)
    tile[ty+j][tx] = S[(long)(r0+ty+j)*C + (c0+tx)];
  __syncthreads();
  #pragma unroll
  for (int j = 0; j < 32; j += 8)
    D[(long)(c0+ty+j)*R + (r0+tx)] = f2bf(tile[tx][ty+j]);
}

__global__ void f32_to_bf16_kernel(const float* src, short* dst){
  int i = blockIdx.x*256 + threadIdx.x;
  dst[i] = f2bf(src[i]);
}

// Order-6 commuting-power split:
// Racc = I + G + G2/2 + G3/6 ; Sb = bf16(G/24 + G2/120 + G3/720)
// (then Racc += Sb @ G3 supplies terms 4..6 exactly)
__global__ void poly6_kernel(const float* gens, const short* G2b, const short* G3b,
                             float* Racc, short* Sb){
  int i = blockIdx.x*256 + threadIdx.x;
  float g  = gens[i];
  float g2 = bf2f(G2b[i]);
  float g3 = bf2f(G3b[i]);
  int w = i & (int)(MELT-1);
  float id = ((w >> 10) == (w & 1023)) ? 1.0f : 0.0f;
  Racc[i] = id + g + 0.5f*g2 + (1.0f/6.0f)*g3;
  Sb[i] = f2bf((1.0f/24.0f)*g + (1.0f/120.0f)*g2 + (1.0f/720.0f)*g3);
}

// -------------------------------------------- LayerNorm + routing fused ----
__global__ __launch_bounds__(256)
void ln_route_kernel(const float* x, const float* g, const float* b,
                     const float* gate_w, const float* gate_b, short* xnb,
                     int* e0a, int* e1a, float* w0a, float* w1a){
  int row = blockIdx.x;
  const float* xr = x + (long)row*DIM;
  f32x4 v = ((const f32x4*)xr)[threadIdx.x];
  float s1 = v[0]+v[1]+v[2]+v[3];
  float s2 = v[0]*v[0]+v[1]*v[1]+v[2]*v[2]+v[3]*v[3];
  #pragma unroll
  for (int o = 32; o; o >>= 1){ s1 += __shfl_xor(s1,o); s2 += __shfl_xor(s2,o); }
  __shared__ float p1[4], p2[4], pl[4][NE];
  int w = threadIdx.x >> 6, l = threadIdx.x & 63;
  if (l == 0){ p1[w] = s1; p2[w] = s2; }
  __syncthreads();
  float mu = (p1[0]+p1[1]+p1[2]+p1[3]) * (1.0f/DIM);
  float ms = (p2[0]+p2[1]+p2[2]+p2[3]) * (1.0f/DIM);
  float rs = rsqrtf(ms - mu*mu + 1e-5f);
  f32x4 gv = ((const f32x4*)g)[threadIdx.x];
  f32x4 bv = ((const f32x4*)b)[threadIdx.x];
  s16x4 ob;
  float lg[NE] = {0.f,0.f,0.f,0.f,0.f,0.f};
  #pragma unroll
  for (int j = 0; j < 4; ++j){
    float t = (v[j]-mu)*rs*gv[j] + bv[j];
    ob[j] = f2bf(t);
    const float* gwr = gate_w + (threadIdx.x*4 + j)*NE;
    #pragma unroll
    for (int e = 0; e < NE; ++e) lg[e] += t * gwr[e];
  }
  ((s16x4*)(xnb + (long)row*DIM))[threadIdx.x] = ob;
  #pragma unroll
  for (int o = 32; o; o >>= 1)
    #pragma unroll
    for (int e = 0; e < NE; ++e) lg[e] += __shfl_xor(lg[e], o);
  if (l == 0)
    #pragma unroll
    for (int e = 0; e < NE; ++e) pl[w][e] = lg[e];
  __syncthreads();
  if (threadIdx.x == 0){
    float s[NE];
    #pragma unroll
    for (int e = 0; e < NE; ++e) s[e] = pl[0][e]+pl[1][e]+pl[2][e]+pl[3][e] + gate_b[e];
    int b0 = 0;
    #pragma unroll
    for (int e = 1; e < NE; ++e) if (s[e] > s[b0]) b0 = e;
    int b1 = -1;
    #pragma unroll
    for (int e = 0; e < NE; ++e){ if (e == b0) continue; if (b1 < 0 || s[e] > s[b1]) b1 = e; }
    float ex = expf(s[b1] - s[b0]);
    float inv = 1.0f/(1.0f + ex);
    e0a[row] = b0; e1a[row] = b1; w0a[row] = inv; w1a[row] = ex*inv;
  }
}

// ---- routing compaction: LDS histogram -> serial prefix -> LDS-cursor scatter
__global__ __launch_bounds__(256)
void hist_kernel(const int* e0, const int* e1, int* blockhist){
  __shared__ int h[NE];
  if (threadIdx.x < NE) h[threadIdx.x] = 0;
  __syncthreads();
  int t = blockIdx.x*256 + threadIdx.x;
  atomicAdd(&h[e0[t]], 1);
  atomicAdd(&h[e1[t]], 1);
  __syncthreads();
  if (threadIdx.x < NE) blockhist[blockIdx.x*NE + threadIdx.x] = h[threadIdx.x];
}

#define NBLK_R (T_TOK/256)
__global__ void prefix2_kernel(const int* blockhist, int* ebase, int* counts, int* blockoff){
  if (threadIdx.x == 0){
    int tot[NE];
    for (int e = 0; e < NE; ++e) tot[e] = 0;
    for (int b = 0; b < NBLK_R; ++b)
      for (int e = 0; e < NE; ++e) tot[e] += blockhist[b*NE + e];
    int base = 0;
    int run[NE];
    for (int e = 0; e < NE; ++e){ ebase[e] = base; counts[e] = tot[e]; run[e] = base; base += tot[e]; }
    for (int b = 0; b < NBLK_R; ++b)
      for (int e = 0; e < NE; ++e){ blockoff[b*NE + e] = run[e]; run[e] += blockhist[b*NE + e]; }
  }
}

__global__ __launch_bounds__(256)
void scatter2_kernel(const int* e0, const int* e1, const float* w0, const float* w1,
                     const int* blockoff, int* ctok, float* cw, int* t2r){
  __shared__ int off[NE];
  if (threadIdx.x < NE) off[threadIdx.x] = blockoff[blockIdx.x*NE + threadIdx.x];
  __syncthreads();
  int t = blockIdx.x*256 + threadIdx.x;
  int a = e0[t], b = e1[t];
  int r0 = atomicAdd(&off[a], 1);
  ctok[r0] = t; cw[r0] = w0[t]; t2r[2*t] = r0;
  int r1 = atomicAdd(&off[b], 1);
  ctok[r1] = t; cw[r1] = w1[t]; t2r[2*t+1] = r1;
}

// nonabel[t] = eo[r0] + eo[r1]
__global__ __launch_bounds__(256)
void combine_kernel(const short* eo, const int* t2r, short* nonab){
  int t = blockIdx.x;
  int r0 = t2r[t*2], r1 = t2r[t*2+1];
  s16x4 a = ((const s16x4*)(eo + (long)r0*DIM))[threadIdx.x];
  s16x4 b = ((const s16x4*)(eo + (long)r1*DIM))[threadIdx.x];
  s16x4 o;
  #pragma unroll
  for (int j = 0; j < 4; ++j) o[j] = f2bf(bf2f(a[j]) + bf2f(b[j]));
  ((s16x4*)(nonab + (long)t*DIM))[threadIdx.x] = o;
}

// out = x + abel*(1-g) + rot*g ;  g = sigmoid([abel,rot] @ gc_w + gc_b)
__global__ __launch_bounds__(256)
void final_kernel(const float* x, const short* abel, const short* rot,
                  const float* gcw, const float* gcb, float* out){
  int t = blockIdx.x;
  f32x4 xv = ((const f32x4*)(x + (long)t*DIM))[threadIdx.x];
  s16x4 av = ((const s16x4*)(abel + (long)t*DIM))[threadIdx.x];
  s16x4 rv = ((const s16x4*)(rot  + (long)t*DIM))[threadIdx.x];
  f32x4 ga = ((const f32x4*)gcw)[threadIdx.x];
  f32x4 gr = ((const f32x4*)(gcw + DIM))[threadIdx.x];
  float af[4], rf[4];
  float s = 0.f;
  #pragma unroll
  for (int j = 0; j < 4; ++j){
    af[j] = bf2f(av[j]); rf[j] = bf2f(rv[j]);
    s += af[j]*ga[j] + rf[j]*gr[j];
  }
  #pragma unroll
  for (int o = 32; o; o >>= 1) s += __shfl_xor(s, o);
  __shared__ float p[4];
  int w = threadIdx.x >> 6, l = threadIdx.x & 63;
  if (l == 0) p[w] = s;
  __syncthreads();
  float tot = p[0]+p[1]+p[2]+p[3] + gcb[0];
  float gate = 1.0f/(1.0f + expf(-tot));
  f32x4 o;
  #pragma unroll
  for (int j = 0; j < 4; ++j) o[j] = xv[j] + af[j]*(1.0f-gate) + rf[j]*gate;
  ((f32x4*)(out + (long)t*DIM))[threadIdx.x] = o;
}

// ---------------------------------------------------------------- host ----
extern "C" void kernel_launch(void* const* d_in, const int* in_sizes, int n_in,
                              void* d_out, int out_size, void* d_ws, size_t ws_size,
                              hipStream_t stream){
  const float* x      = (const float*)d_in[0];
  const float* ln_g   = (const float*)d_in[1];
  const float* ln_b   = (const float*)d_in[2];
  const float* aw1    = (const float*)d_in[3];
  const float* ab1    = (const float*)d_in[4];
  const float* aw2    = (const float*)d_in[5];
  const float* ab2    = (const float*)d_in[6];
  const float* gate_w = (const float*)d_in[7];
  const float* gate_b = (const float*)d_in[8];
  const float* ew1    = (const float*)d_in[9];
  const float* eb1    = (const float*)d_in[10];
  const float* ew2    = (const float*)d_in[11];
  const float* eb2    = (const float*)d_in[12];
  const float* gens   = (const float*)d_in[13];
  const float* gc_w   = (const float*)d_in[14];
  const float* gc_b   = (const float*)d_in[15];
  float* out = (float*)d_out;
  (void)in_sizes; (void)n_in; (void)out_size; (void)ws_size;

  char* ws = (char*)d_ws;
  // expm scratch (dead before weights/acts overlay)
  short* Gb    = (short*)(ws +   0*MB);
  short* GbT   = (short*)(ws +   8*MB);
  short* G2b   = (short*)(ws +  16*MB);
  short* G3b   = (short*)(ws +  32*MB);
  short* G3bT  = (short*)(ws +  48*MB);
  float* Racc  = (float*)(ws +  64*MB);
  short* Sb    = (short*)(ws +  80*MB);
  short* Rb    = (short*)(ws +  88*MB);
  short* RbT   = (short*)(ws +  96*MB);
  short* Mpair = (short*)(ws + 104*MB);
  short* MpairT= (short*)(ws + 106*MB);
  // weights / activations
  short* aw1bT = (short*)(ws +   0*MB);
  short* aw2bT = (short*)(ws +   8*MB);
  short* ew1bT = (short*)(ws +  16*MB);
  short* ew2bT = (short*)(ws +  40*MB);
  short* xn_bf = (short*)(ws +  64*MB);
  short* rot   = (short*)(ws +  64*MB);
  short* hsh   = (short*)(ws +  80*MB);
  short* nonab = (short*)(ws +  80*MB);
  short* abel  = (short*)(ws + 144*MB);
  short* eo    = (short*)(ws + 160*MB);
  short* MbT   = (short*)(ws + 192*MB);
  // small
  int*   counts   = (int*)  (ws + 194*MB);
  int*   ebase    = (int*)  (ws + 194*MB + 1024);
  int*   blockhist= (int*)  (ws + 194*MB + 2048);
  int*   blockoff = (int*)  (ws + 194*MB + 4096);
  int*   e0a   = (int*)  (ws + 194*MB +  64*1024);
  int*   e1a   = (int*)  (ws + 194*MB +  96*1024);
  float* w0a   = (float*)(ws + 194*MB + 128*1024);
  float* w1a   = (float*)(ws + 194*MB + 160*1024);
  int*   ctok  = (int*)  (ws + 194*MB + 192*1024);
  float* cw    = (float*)(ws + 194*MB + 256*1024);
  int*   t2r   = (int*)  (ws + 194*MB + 320*1024);

  // ---- stage a: M = expm(g0)..expm(g3), order-6 Taylor (commuting split)
  transpose_f32_to_bf16<<<dim3(32, 32, 4), 256, 0, stream>>>(gens, GbT, DIM, DIM, MELT, MELT);
  f32_to_bf16_kernel<<<4*MELT/256, 256, 0, stream>>>(gens, Gb);
  { // G2 = G*G (z=4)
    GemmArgs ga{}; ga.A = Gb; ga.BT = GbT; ga.sA = MELT; ga.sBT = MELT;
    ga.Cb = G2b; ga.sCb = MELT; ga.alpha = 1.f;
    ga.M = DIM; ga.N = DIM; ga.K = DIM; ga.lda = DIM; ga.ldb = DIM; ga.ldc = DIM;
    gemm_kernel<2,2><<<dim3(16, 16, 4), 256, 0, stream>>>(ga);
  }
  { // G3 = G2*G (z=4), keep row-major + transposed
    GemmArgs ga{}; ga.A = G2b; ga.BT = GbT; ga.sA = MELT; ga.sBT = MELT;
    ga.Cb = G3b; ga.sCb = MELT; ga.CbT = G3bT; ga.sCbT = MELT; ga.ldcbt = DIM;
    ga.alpha = 1.f;
    ga.M = DIM; ga.N = DIM; ga.K = DIM; ga.lda = DIM; ga.ldb = DIM; ga.ldc = DIM;
    gemm_kernel<2,2><<<dim3(16, 16, 4), 256, 0, stream>>>(ga);
  }
  poly6_kernel<<<4*MELT/256, 256, 0, stream>>>(gens, G2b, G3b, Racc, Sb);
  { // Racc += S*G3  (supplies Taylor terms 4..6 exactly)
    GemmArgs ga{}; ga.A = Sb; ga.BT = G3bT; ga.sA = MELT; ga.sBT = MELT;
    ga.Racc = Racc; ga.sR = MELT; ga.alpha = 1.f;
    ga.M = DIM; ga.N = DIM; ga.K = DIM; ga.lda = DIM; ga.ldb = DIM; ga.ldc = DIM;
    gemm_kernel<2,2><<<dim3(16, 16, 4), 256, 0, stream>>>(ga);
  }
  f32_to_bf16_kernel<<<4*MELT/256, 256, 0, stream>>>(Racc, Rb);
  transpose_f32_to_bf16<<<dim3(32, 32, 3), 256, 0, stream>>>(Racc + MELT, RbT, DIM, DIM, MELT, MELT);
  { // z=0: M01 = R0*R1 ; z=1: M23 = R2*R3
    GemmArgs ga{}; ga.A = Rb; ga.BT = RbT; ga.sA = 2*MELT; ga.sBT = 2*MELT;
    ga.Cb = Mpair; ga.sCb = MELT; ga.CbT = MpairT; ga.sCbT = MELT; ga.ldcbt = DIM;
    ga.alpha = 1.f;
    ga.M = DIM; ga.N = DIM; ga.K = DIM; ga.lda = DIM; ga.ldb = DIM; ga.ldc = DIM;
    gemm_kernel<2,2><<<dim3(16, 16, 2), 256, 0, stream>>>(ga);
  }
  { // M = M01*M23, stored transposed
    GemmArgs ga{}; ga.A = Mpair; ga.BT = MpairT + MELT;
    ga.CbT = MbT; ga.ldcbt = DIM; ga.alpha = 1.f;
    ga.M = DIM; ga.N = DIM; ga.K = DIM; ga.lda = DIM; ga.ldb = DIM; ga.ldc = DIM;
    gemm_kernel<2,2><<<dim3(16, 16, 1), 256, 0, stream>>>(ga);
  }

  // ---- stage b: weight conversions (f32 -> bf16 [N,K])
  transpose_f32_to_bf16<<<dim3(A4D/32, DIM/32, 1), 256, 0, stream>>>(aw1, aw1bT, DIM, A4D, 0, 0);
  transpose_f32_to_bf16<<<dim3(DIM/32, A4D/32, 1), 256, 0, stream>>>(aw2, aw2bT, A4D, DIM, 0, 0);
  transpose_f32_to_bf16<<<dim3(HDIM/32, DIM/32, NE), 256, 0, stream>>>(ew1, ew1bT, DIM, HDIM, (long)DIM*HDIM, (long)DIM*HDIM);
  transpose_f32_to_bf16<<<dim3(DIM/32, HDIM/32, NE), 256, 0, stream>>>(ew2, ew2bT, HDIM, DIM, (long)DIM*HDIM, (long)DIM*HDIM);

  // ---- stage c: LayerNorm + routing, atomic-free compaction
  ln_route_kernel<<<T_TOK, 256, 0, stream>>>(x, ln_g, ln_b, gate_w, gate_b,
                                             xn_bf, e0a, e1a, w0a, w1a);
  hist_kernel<<<NBLK_R, 256, 0, stream>>>(e0a, e1a, blockhist);
  prefix2_kernel<<<1, 64, 0, stream>>>(blockhist, ebase, counts, blockoff);
  scatter2_kernel<<<NBLK_R, 256, 0, stream>>>(e0a, e1a, w0a, w1a, blockoff, ctok, cw, t2r);

  // ---- stage d: abel branch
  {
    GemmArgs ga{}; ga.A = xn_bf; ga.BT = aw1bT; ga.Cb = hsh;
    ga.bias = ab1; ga.alpha = 1.f; ga.do_gelu = 1;
    ga.M = T_TOK; ga.N = A4D; ga.K = DIM; ga.lda = DIM; ga.ldb = DIM; ga.ldc = A4D;
    gemm_sq256<<<dim3(A4D/256, T_TOK/256, 1), 1024, 0, stream>>>(ga);
  }
  {
    GemmArgs ga{}; ga.A = hsh; ga.BT = aw2bT; ga.Cb = abel;
    ga.bias = ab2; ga.alpha = 1.f;
    ga.M = T_TOK; ga.N = DIM; ga.K = A4D; ga.lda = A4D; ga.ldb = A4D; ga.ldc = DIM;
    gemm_kernel<4,4><<<dim3(DIM/128, T_TOK/128, 1), 256, 0, stream>>>(ga);
  }

  // ---- experts (gathered top-2)
  {
    GemmArgs ga{}; ga.mode = 1; ga.A = xn_bf; ga.BT = ew1bT; ga.sBT = (long)HDIM*DIM;
    ga.Cb = hsh; ga.bias = eb1; ga.sBias = HDIM; ga.alpha = 1.f; ga.do_gelu = 1;
    ga.toklist = ctok; ga.ebase = ebase; ga.ecount = counts;
    ga.M = T_TOK; ga.N = HDIM; ga.K = DIM; ga.lda = DIM; ga.ldb = DIM; ga.ldc = HDIM;
    gemm_sq256<<<dim3(HDIM/256, T_TOK/256, NE), 1024, 0, stream>>>(ga);
  }
  {
    GemmArgs ga{}; ga.mode = 2; ga.A = hsh; ga.BT = ew2bT; ga.sBT = (long)DIM*HDIM;
    ga.Cb = eo; ga.bias = eb2; ga.sBias = DIM; ga.rowscale = cw; ga.alpha = 1.f;
    ga.ebase = ebase; ga.ecount = counts;
    ga.M = T_TOK; ga.N = DIM; ga.K = HDIM; ga.lda = HDIM; ga.ldb = HDIM; ga.ldc = DIM;
    gemm_kernel<4,4><<<dim3(DIM/128, T_TOK/128, NE), 256, 0, stream>>>(ga);
  }
  combine_kernel<<<T_TOK, 256, 0, stream>>>(eo, t2r, nonab);

  // ---- rot = nonabel @ M
  {
    GemmArgs ga{}; ga.A = nonab; ga.BT = MbT; ga.Cb = rot; ga.alpha = 1.f;
    ga.M = T_TOK; ga.N = DIM; ga.K = DIM; ga.lda = DIM; ga.ldb = DIM; ga.ldc = DIM;
    gemm_kernel<4,4><<<dim3(DIM/128, T_TOK/128, 1), 256, 0, stream>>>(ga);
  }

  final_kernel<<<T_TOK, 256, 0, stream>>>(x, abel, rot, gc_w, gc_b, out);
}

// Round 12
// 757.235 us; speedup vs baseline: 1.3956x; 1.0457x over previous
//
#include <hip/hip_runtime.h>
#include <hip/hip_bf16.h>

#define T_TOK 8192
#define DIM   1024
#define A4D   4096
#define HDIM  2048
#define NE    6
#define MB    ((size_t)1 << 20)
#define MELT  1048576L   // elements in a 1024x1024 matrix

typedef __attribute__((ext_vector_type(4))) float f32x4;
typedef __attribute__((ext_vector_type(8))) short bf16x8;
typedef __attribute__((ext_vector_type(4))) short s16x4;

__device__ __forceinline__ float bf2f(short b){
  union { unsigned u; float f; } c; c.u = ((unsigned)(unsigned short)b) << 16; return c.f;
}
__device__ __forceinline__ short f2bf(float f){
  union { float f; unsigned u; } c; c.f = f;
  unsigned u = c.u;
  unsigned r = (u + 0x7fffu + ((u >> 16) & 1u)) >> 16;
  return (short)r;
}

// gelu via Abramowitz-Stegun 7.1.26 erf (max abs err 1.5e-7) — ~2x cheaper
// than libm erff. gelu(v) = 0.5 v (1 + erf(v/sqrt2)).
__device__ __forceinline__ float fast_gelu(float v){
  float x  = v * 0.70710678118654752f;
  float ax = fabsf(x);
  float t  = __builtin_amdgcn_rcpf(1.0f + 0.3275911f*ax);
  float p  = ((((1.061405429f*t - 1.453152027f)*t + 1.421413741f)*t
               - 0.284496736f)*t + 0.254829592f)*t;
  float e  = __expf(-ax*ax);
  float er = 1.0f - p*e;
  er = (x < 0.0f) ? -er : er;
  return 0.5f*v*(1.0f + er);
}

__device__ __forceinline__ void gl_lds16(const short* g, short* l){
  __builtin_amdgcn_global_load_lds(
      (const __attribute__((address_space(1))) void*)g,
      (__attribute__((address_space(3))) void*)l, 16, 0, 0);
}

template<int N> __device__ __forceinline__ void wait_vmcnt(){
  if constexpr (N >= 8)      asm volatile("s_waitcnt vmcnt(8)" ::: "memory");
  else if constexpr (N == 4) asm volatile("s_waitcnt vmcnt(4)" ::: "memory");
  else if constexpr (N == 2) asm volatile("s_waitcnt vmcnt(2)" ::: "memory");
  else                       asm volatile("s_waitcnt vmcnt(0)" ::: "memory");
}

// ---------------------------------------------------------------- GEMM ----
// C[M,N] = A[M,K](bf16,row-major) @ B (given as BT[N,K] bf16 row-major)
// mode 0: simple (z-batched via strides)
// mode 1: expert gather-A (A rows via toklist, M = ecount[z])
// mode 2: expert contiguous-A (A += ebase[z]*lda, M = ecount[z])
// Racc (if set): v += Racc[idx] (read-add, no writeback) before bias/act.
struct GemmArgs {
  const short* A; const short* BT; const short* BT2;
  long sA, sBT;
  short* Cb; short* CbT; float* Racc;
  long sCb, sCbT, sR;
  const float* bias; long sBias;
  const float* rowscale;
  const int* toklist; const int* ebase; const int* ecount;
  float alpha;
  int M, N, K, lda, ldb, ldc, ldcbt;
  int mode, do_gelu;
};

// ===== 128-class kernel: 256 threads, 4 waves (2x2), depth-3 counted vmcnt.
// Proven at R5/R8. Used for expm path and all N=1024 GEMMs.
template<int MF, int NF>
__global__ __launch_bounds__(256)
void gemm_kernel(GemmArgs g){
  constexpr int BM = 32*MF, BN = 32*NF;
  constexpr int CA = (BM*32)/2048;
  constexpr int CB = (BN*32)/2048;
  constexpr int PS = CA + CB;
  const int z  = blockIdx.z;

  int bx = blockIdx.x, by = blockIdx.y;
  {
    int gx = gridDim.x, gy = gridDim.y;
    if ((gy & 7) == 0){
      int linear = by*gx + bx;
      int per = gx << 3;
      int grp = linear / per, rem = linear % per;
      bx = rem >> 3;
      by = (grp << 3) + (rem & 7);
    }
  }
  const int m0 = by * BM;
  const int n0 = bx * BN;

  const short* A; const short* BT;
  const int* rows = nullptr;
  int M = g.M;
  int rowbase = 0;
  if (g.mode == 0){
    A  = g.A  + (long)z * g.sA;
    BT = g.BT + (long)z * g.sBT;
  } else {
    int cnt = g.ecount[z];
    if (m0 >= cnt) return;
    M = cnt;
    rowbase = g.ebase[z];
    BT = g.BT + (long)z * g.sBT;
    if (g.mode == 1){ A = g.A; rows = g.toklist + rowbase; }
    else            { A = g.A + (long)rowbase * g.lda; }
  }

  __shared__ __align__(16) short As[3][BM*32];
  __shared__ __align__(16) short Bs[3][BN*32];

  const int tid  = threadIdx.x;
  const int wid  = tid >> 6;
  const int lane = tid & 63;
  const int wr = wid >> 1, wc = wid & 1;
  const int lrow = lane & 15, lgrp = lane >> 4;

  const short* aP[CA]; const short* bP[CB];
  int aDoff[CA], bDoff[CB];
  #pragma unroll
  for (int c = 0; c < CA; ++c){
    int q = c*256 + tid;
    int r = q >> 2;
    int colel = ((q & 3) ^ ((r >> 1) & 3)) * 8;
    long arow;
    if (g.mode == 1){
      int rr = m0 + r; if (rr > M-1) rr = M-1;
      arow = rows[rr];
    } else if (g.mode == 2){
      int rr = m0 + r; if (rr > M-1) rr = M-1;
      arow = rr;
    } else {
      arow = m0 + r;
    }
    aP[c] = A + arow * (long)g.lda + colel;
    aDoff[c] = (c*256 + wid*64) * 8;
  }
  #pragma unroll
  for (int c = 0; c < CB; ++c){
    int q = c*256 + tid;
    int r = q >> 2;
    int colel = ((q & 3) ^ ((r >> 1) & 3)) * 8;
    bP[c] = BT + (long)(n0 + r) * g.ldb + colel;
    bDoff[c] = (c*256 + wid*64) * 8;
  }

  f32x4 acc[MF][NF];
  #pragma unroll
  for (int i = 0; i < MF; ++i)
    #pragma unroll
    for (int j = 0; j < NF; ++j) acc[i][j] = (f32x4){0.f,0.f,0.f,0.f};

  int aRoff[MF], bRoff[NF];
  #pragma unroll
  for (int mi = 0; mi < MF; ++mi){
    int R = wr*(16*MF) + mi*16 + lrow;
    aRoff[mi] = R*32 + ((lgrp ^ ((R >> 1) & 3)) * 8);
  }
  #pragma unroll
  for (int ni = 0; ni < NF; ++ni){
    int R = wc*(16*NF) + ni*16 + lrow;
    bRoff[ni] = R*32 + ((lgrp ^ ((R >> 1) & 3)) * 8);
  }

  auto stage = [&](int buf, int ko){
    #pragma unroll
    for (int c = 0; c < CA; ++c) gl_lds16(aP[c] + ko, &As[buf][aDoff[c]]);
    #pragma unroll
    for (int c = 0; c < CB; ++c) gl_lds16(bP[c] + ko, &Bs[buf][bDoff[c]]);
  };

  const int nk = g.K / 32;   // must be >= 3
  stage(0, 0); stage(1, 32); stage(2, 64);
  int buf = 0;
  for (int t = 0; t < nk; ++t){
    if (t < nk-2)       wait_vmcnt<2*PS>();
    else if (t == nk-2) wait_vmcnt<PS>();
    else                wait_vmcnt<0>();
    asm volatile("s_barrier" ::: "memory");
    bf16x8 af[MF], bfr[NF];
    #pragma unroll
    for (int mi = 0; mi < MF; ++mi)
      af[mi] = *(const bf16x8*)&As[buf][aRoff[mi]];
    #pragma unroll
    for (int ni = 0; ni < NF; ++ni)
      bfr[ni] = *(const bf16x8*)&Bs[buf][bRoff[ni]];
    asm volatile("s_waitcnt lgkmcnt(0)" ::: "memory");
    asm volatile("s_barrier" ::: "memory");
    if (t + 3 < nk) stage(buf, (t + 3) * 32);
    #pragma unroll
    for (int mi = 0; mi < MF; ++mi)
      #pragma unroll
      for (int ni = 0; ni < NF; ++ni)
        acc[mi][ni] = __builtin_amdgcn_mfma_f32_16x16x32_bf16(af[mi], bfr[ni], acc[mi][ni], 0, 0, 0);
    buf = (buf == 2) ? 0 : buf + 1;
  }

  #pragma unroll
  for (int mi = 0; mi < MF; ++mi){
    #pragma unroll
    for (int ni = 0; ni < NF; ++ni){
      int gc = n0 + wc*(16*NF) + ni*16 + lrow;
      #pragma unroll
      for (int j = 0; j < 4; ++j){
        int gr = m0 + wr*(16*MF) + mi*16 + lgrp*4 + j;
        if ((g.mode == 1 || g.mode == 2) && gr >= M) continue;
        float v = acc[mi][ni][j] * g.alpha;
        if (g.Racc)     v += g.Racc[(long)z*g.sR + (long)gr*g.ldc + gc];
        if (g.bias)     v += g.bias[(long)z*g.sBias + gc];
        if (g.rowscale) v *= g.rowscale[rowbase + gr];
        if (g.do_gelu)  v = fast_gelu(v);
        long ro = (long)rowbase + gr;
        if (g.Cb)   g.Cb[(long)z*g.sCb + ro*(long)g.ldc + gc] = f2bf(v);
        if (g.CbT)  g.CbT[(long)z*g.sCbT + (long)gc*g.ldcbt + ro] = f2bf(v);
      }
    }
  }
}

// ===== 256-sq kernel: 1024 threads, 16 waves (4x4), per-wave 64x64 (acc[4][4]),
// BK=32, 64KB LDS, 2 blocks/CU. Proven at R8 (824us). Modes 0 and 1 only.
__global__ __launch_bounds__(1024)
void gemm_sq256(GemmArgs g){
  constexpr int BM = 256, BN = 256;
  const int z  = blockIdx.z;

  int bx = blockIdx.x, by = blockIdx.y;
  {
    int gx = gridDim.x, gy = gridDim.y;
    if ((gy & 7) == 0){
      int linear = by*gx + bx;
      int per = gx << 3;
      int grp = linear / per, rem = linear % per;
      bx = rem >> 3;
      by = (grp << 3) + (rem & 7);
    }
  }
  const int m0 = by * BM;
  const int n0 = bx * BN;

  const short* A; const short* BT;
  const int* rows = nullptr;
  int M = g.M;
  int rowbase = 0;
  if (g.mode == 0){
    A  = g.A  + (long)z * g.sA;
    BT = g.BT + (long)z * g.sBT;
  } else {
    int cnt = g.ecount[z];
    if (m0 >= cnt) return;
    M = cnt;
    rowbase = g.ebase[z];
    BT = g.BT + (long)z * g.sBT;
    A = g.A; rows = g.toklist + rowbase;   // mode 1
  }

  __shared__ __align__(16) short As[2][BM*32];
  __shared__ __align__(16) short Bs[2][BN*32];

  const int tid  = threadIdx.x;
  const int wid  = tid >> 6;         // 0..15
  const int lane = tid & 63;
  const int wr = wid >> 2, wc = wid & 3;   // 4x4 wave grid
  const int lrow = lane & 15, lgrp = lane >> 4;

  // staging: 1024 threads cover 256 rows x 32 cols (1 call each for A and B)
  const short* aP; const short* bP;
  int dOff;
  {
    int q = tid;
    int r = q >> 2;
    int colel = ((q & 3) ^ ((r >> 1) & 3)) * 8;
    long arow;
    if (g.mode == 1){
      int rr = m0 + r; if (rr > M-1) rr = M-1;
      arow = rows[rr];
    } else {
      arow = m0 + r;
    }
    aP = A + arow * (long)g.lda + colel;
    bP = BT + (long)(n0 + r) * g.ldb + colel;
    dOff = (wid*64) * 8;
  }

  f32x4 acc[4][4];
  #pragma unroll
  for (int i = 0; i < 4; ++i)
    #pragma unroll
    for (int j = 0; j < 4; ++j) acc[i][j] = (f32x4){0.f,0.f,0.f,0.f};

  int aRoff[4], bRoff[4];
  #pragma unroll
  for (int mi = 0; mi < 4; ++mi){
    int R = wr*64 + mi*16 + lrow;
    aRoff[mi] = R*32 + ((lgrp ^ ((R >> 1) & 3)) * 8);
  }
  #pragma unroll
  for (int ni = 0; ni < 4; ++ni){
    int R = wc*64 + ni*16 + lrow;
    bRoff[ni] = R*32 + ((lgrp ^ ((R >> 1) & 3)) * 8);
  }

  auto stage = [&](int buf, int ko){
    gl_lds16(aP + ko, &As[buf][dOff]);
    gl_lds16(bP + ko, &Bs[buf][dOff]);
  };

  const int nk = g.K / 32;
  stage(0, 0);
  __syncthreads();
  int buf = 0;
  for (int t = 0; t < nk; ++t){
    if (t + 1 < nk) stage(buf ^ 1, (t + 1) * 32);
    bf16x8 af[4], bfr[4];
    #pragma unroll
    for (int mi = 0; mi < 4; ++mi)
      af[mi] = *(const bf16x8*)&As[buf][aRoff[mi]];
    #pragma unroll
    for (int ni = 0; ni < 4; ++ni)
      bfr[ni] = *(const bf16x8*)&Bs[buf][bRoff[ni]];
    #pragma unroll
    for (int mi = 0; mi < 4; ++mi)
      #pragma unroll
      for (int ni = 0; ni < 4; ++ni)
        acc[mi][ni] = __builtin_amdgcn_mfma_f32_16x16x32_bf16(af[mi], bfr[ni], acc[mi][ni], 0, 0, 0);
    __syncthreads();
    buf ^= 1;
  }

  #pragma unroll
  for (int mi = 0; mi < 4; ++mi){
    #pragma unroll
    for (int ni = 0; ni < 4; ++ni){
      int gc = n0 + wc*64 + ni*16 + lrow;
      #pragma unroll
      for (int j = 0; j < 4; ++j){
        int gr = m0 + wr*64 + mi*16 + lgrp*4 + j;
        if (g.mode == 1 && gr >= M) continue;
        float v = acc[mi][ni][j] * g.alpha;
        if (g.bias)     v += g.bias[(long)z*g.sBias + gc];
        if (g.rowscale) v *= g.rowscale[rowbase + gr];
        if (g.do_gelu)  v = fast_gelu(v);
        long ro = (long)rowbase + gr;
        if (g.Cb) g.Cb[(long)z*g.sCb + ro*(long)g.ldc + gc] = f2bf(v);
      }
    }
  }
}

// ------------------------------------------------------- transpose conv ----
// dst[C,R] (bf16) = transpose(src[R,C] f32); optional dstRow = bf16 row-major
__global__ __launch_bounds__(256)
void transpose_f32_to_bf16(const float* src, short* dst, int R, int C,
                           long sSrc, long sDst, short* dstRow, long sDstRow){
  __shared__ float tile[32][33];
  const float* S = src + (long)blockIdx.z * sSrc;
  short* D = dst + (long)blockIdx.z * sDst;
  int c0 = blockIdx.x*32, r0 = blockIdx.y*32;
  int tx = threadIdx.x & 31;
  int ty = threadIdx.x >> 5;
  #pragma unroll
  for (int j = 0; j < 32; j += 8){
    float v = S[(long)(r0+ty+j)*C + (c0+tx)];
    tile[ty+j][tx] = v;
    if (dstRow)
      dstRow[(long)blockIdx.z * sDstRow + (long)(r0+ty+j)*C + (c0+tx)] = f2bf(v);
  }
  __syncthreads();
  #pragma unroll
  for (int j = 0; j < 32; j += 8)
    D[(long)(c0+ty+j)*R + (r0+tx)] = f2bf(tile[tx][ty+j]);
}

// Order-6 commuting-power split:
// Racc = I + G + G2/2 + G3/6 ; Sb = bf16(G/24 + G2/120 + G3/720)
// (then R = Racc + Sb @ G3 supplies terms 4..6 exactly)
__global__ void poly6_kernel(const float* gens, const short* G2b, const short* G3b,
                             float* Racc, short* Sb){
  int i = blockIdx.x*256 + threadIdx.x;
  float g  = gens[i];
  float g2 = bf2f(G2b[i]);
  float g3 = bf2f(G3b[i]);
  int w = i & (int)(MELT-1);
  float id = ((w >> 10) == (w & 1023)) ? 1.0f : 0.0f;
  Racc[i] = id + g + 0.5f*g2 + (1.0f/6.0f)*g3;
  Sb[i] = f2bf((1.0f/24.0f)*g + (1.0f/120.0f)*g2 + (1.0f/720.0f)*g3);
}

// -------------------------------------------- LayerNorm + routing fused ----
__global__ __launch_bounds__(256)
void ln_route_kernel(const float* x, const float* g, const float* b,
                     const float* gate_w, const float* gate_b, short* xnb,
                     int* e0a, int* e1a, float* w0a, float* w1a){
  int row = blockIdx.x;
  const float* xr = x + (long)row*DIM;
  f32x4 v = ((const f32x4*)xr)[threadIdx.x];
  float s1 = v[0]+v[1]+v[2]+v[3];
  float s2 = v[0]*v[0]+v[1]*v[1]+v[2]*v[2]+v[3]*v[3];
  #pragma unroll
  for (int o = 32; o; o >>= 1){ s1 += __shfl_xor(s1,o); s2 += __shfl_xor(s2,o); }
  __shared__ float p1[4], p2[4], pl[4][NE];
  int w = threadIdx.x >> 6, l = threadIdx.x & 63;
  if (l == 0){ p1[w] = s1; p2[w] = s2; }
  __syncthreads();
  float mu = (p1[0]+p1[1]+p1[2]+p1[3]) * (1.0f/DIM);
  float ms = (p2[0]+p2[1]+p2[2]+p2[3]) * (1.0f/DIM);
  float rs = rsqrtf(ms - mu*mu + 1e-5f);
  f32x4 gv = ((const f32x4*)g)[threadIdx.x];
  f32x4 bv = ((const f32x4*)b)[threadIdx.x];
  s16x4 ob;
  float lg[NE] = {0.f,0.f,0.f,0.f,0.f,0.f};
  #pragma unroll
  for (int j = 0; j < 4; ++j){
    float t = (v[j]-mu)*rs*gv[j] + bv[j];
    ob[j] = f2bf(t);
    const float* gwr = gate_w + (threadIdx.x*4 + j)*NE;
    #pragma unroll
    for (int e = 0; e < NE; ++e) lg[e] += t * gwr[e];
  }
  ((s16x4*)(xnb + (long)row*DIM))[threadIdx.x] = ob;
  #pragma unroll
  for (int o = 32; o; o >>= 1)
    #pragma unroll
    for (int e = 0; e < NE; ++e) lg[e] += __shfl_xor(lg[e], o);
  if (l == 0)
    #pragma unroll
    for (int e = 0; e < NE; ++e) pl[w][e] = lg[e];
  __syncthreads();
  if (threadIdx.x == 0){
    float s[NE];
    #pragma unroll
    for (int e = 0; e < NE; ++e) s[e] = pl[0][e]+pl[1][e]+pl[2][e]+pl[3][e] + gate_b[e];
    int b0 = 0;
    #pragma unroll
    for (int e = 1; e < NE; ++e) if (s[e] > s[b0]) b0 = e;
    int b1 = -1;
    #pragma unroll
    for (int e = 0; e < NE; ++e){ if (e == b0) continue; if (b1 < 0 || s[e] > s[b1]) b1 = e; }
    float ex = expf(s[b1] - s[b0]);
    float inv = 1.0f/(1.0f + ex);
    e0a[row] = b0; e1a[row] = b1; w0a[row] = inv; w1a[row] = ex*inv;
  }
}

// ---- routing compaction: LDS histogram -> serial prefix -> LDS-cursor scatter
__global__ __launch_bounds__(256)
void hist_kernel(const int* e0, const int* e1, int* blockhist){
  __shared__ int h[NE];
  if (threadIdx.x < NE) h[threadIdx.x] = 0;
  __syncthreads();
  int t = blockIdx.x*256 + threadIdx.x;
  atomicAdd(&h[e0[t]], 1);
  atomicAdd(&h[e1[t]], 1);
  __syncthreads();
  if (threadIdx.x < NE) blockhist[blockIdx.x*NE + threadIdx.x] = h[threadIdx.x];
}

#define NBLK_R (T_TOK/256)
__global__ void prefix2_kernel(const int* blockhist, int* ebase, int* counts, int* blockoff){
  if (threadIdx.x == 0){
    int tot[NE];
    for (int e = 0; e < NE; ++e) tot[e] = 0;
    for (int b = 0; b < NBLK_R; ++b)
      for (int e = 0; e < NE; ++e) tot[e] += blockhist[b*NE + e];
    int base = 0;
    int run[NE];
    for (int e = 0; e < NE; ++e){ ebase[e] = base; counts[e] = tot[e]; run[e] = base; base += tot[e]; }
    for (int b = 0; b < NBLK_R; ++b)
      for (int e = 0; e < NE; ++e){ blockoff[b*NE + e] = run[e]; run[e] += blockhist[b*NE + e]; }
  }
}

__global__ __launch_bounds__(256)
void scatter2_kernel(const int* e0, const int* e1, const float* w0, const float* w1,
                     const int* blockoff, int* ctok, float* cw, int* t2r){
  __shared__ int off[NE];
  if (threadIdx.x < NE) off[threadIdx.x] = blockoff[blockIdx.x*NE + threadIdx.x];
  __syncthreads();
  int t = blockIdx.x*256 + threadIdx.x;
  int a = e0[t], b = e1[t];
  int r0 = atomicAdd(&off[a], 1);
  ctok[r0] = t; cw[r0] = w0[t]; t2r[2*t] = r0;
  int r1 = atomicAdd(&off[b], 1);
  ctok[r1] = t; cw[r1] = w1[t]; t2r[2*t+1] = r1;
}

// nonabel[t] = eo[r0] + eo[r1]
__global__ __launch_bounds__(256)
void combine_kernel(const short* eo, const int* t2r, short* nonab){
  int t = blockIdx.x;
  int r0 = t2r[t*2], r1 = t2r[t*2+1];
  s16x4 a = ((const s16x4*)(eo + (long)r0*DIM))[threadIdx.x];
  s16x4 b = ((const s16x4*)(eo + (long)r1*DIM))[threadIdx.x];
  s16x4 o;
  #pragma unroll
  for (int j = 0; j < 4; ++j) o[j] = f2bf(bf2f(a[j]) + bf2f(b[j]));
  ((s16x4*)(nonab + (long)t*DIM))[threadIdx.x] = o;
}

// out = x + abel*(1-g) + rot*g ;  g = sigmoid([abel,rot] @ gc_w + gc_b)
__global__ __launch_bounds__(256)
void final_kernel(const float* x, const short* abel, const short* rot,
                  const float* gcw, const float* gcb, float* out){
  int t = blockIdx.x;
  f32x4 xv = ((const f32x4*)(x + (long)t*DIM))[threadIdx.x];
  s16x4 av = ((const s16x4*)(abel + (long)t*DIM))[threadIdx.x];
  s16x4 rv = ((const s16x4*)(rot  + (long)t*DIM))[threadIdx.x];
  f32x4 ga = ((const f32x4*)gcw)[threadIdx.x];
  f32x4 gr = ((const f32x4*)(gcw + DIM))[threadIdx.x];
  float af[4], rf[4];
  float s = 0.f;
  #pragma unroll
  for (int j = 0; j < 4; ++j){
    af[j] = bf2f(av[j]); rf[j] = bf2f(rv[j]);
    s += af[j]*ga[j] + rf[j]*gr[j];
  }
  #pragma unroll
  for (int o = 32; o; o >>= 1) s += __shfl_xor(s, o);
  __shared__ float p[4];
  int w = threadIdx.x >> 6, l = threadIdx.x & 63;
  if (l == 0) p[w] = s;
  __syncthreads();
  float tot = p[0]+p[1]+p[2]+p[3] + gcb[0];
  float gate = 1.0f/(1.0f + expf(-tot));
  f32x4 o;
  #pragma unroll
  for (int j = 0; j < 4; ++j) o[j] = xv[j] + af[j]*(1.0f-gate) + rf[j]*gate;
  ((f32x4*)(out + (long)t*DIM))[threadIdx.x] = o;
}

// ---------------------------------------------------------------- host ----
extern "C" void kernel_launch(void* const* d_in, const int* in_sizes, int n_in,
                              void* d_out, int out_size, void* d_ws, size_t ws_size,
                              hipStream_t stream){
  const float* x      = (const float*)d_in[0];
  const float* ln_g   = (const float*)d_in[1];
  const float* ln_b   = (const float*)d_in[2];
  const float* aw1    = (const float*)d_in[3];
  const float* ab1    = (const float*)d_in[4];
  const float* aw2    = (const float*)d_in[5];
  const float* ab2    = (const float*)d_in[6];
  const float* gate_w = (const float*)d_in[7];
  const float* gate_b = (const float*)d_in[8];
  const float* ew1    = (const float*)d_in[9];
  const float* eb1    = (const float*)d_in[10];
  const float* ew2    = (const float*)d_in[11];
  const float* eb2    = (const float*)d_in[12];
  const float* gens   = (const float*)d_in[13];
  const float* gc_w   = (const float*)d_in[14];
  const float* gc_b   = (const float*)d_in[15];
  float* out = (float*)d_out;
  (void)in_sizes; (void)n_in; (void)out_size; (void)ws_size;

  char* ws = (char*)d_ws;
  // expm scratch (dead before weights/acts overlay)
  short* Gb    = (short*)(ws +   0*MB);
  short* GbT   = (short*)(ws +   8*MB);
  short* G2b   = (short*)(ws +  16*MB);
  short* G3b   = (short*)(ws +  32*MB);
  short* G3bT  = (short*)(ws +  48*MB);
  float* Racc  = (float*)(ws +  64*MB);
  short* Sb    = (short*)(ws +  80*MB);
  short* Rb    = (short*)(ws +  88*MB);
  short* RbT4  = (short*)(ws +  96*MB);   // 4 slots: [R0^T(unused),R1^T,R2^T,R3^T]
  short* Mpair = (short*)(ws + 104*MB);
  short* MpairT= (short*)(ws + 106*MB);
  // weights / activations
  short* aw1bT = (short*)(ws +   0*MB);
  short* aw2bT = (short*)(ws +   8*MB);
  short* ew1bT = (short*)(ws +  16*MB);
  short* ew2bT = (short*)(ws +  40*MB);
  short* xn_bf = (short*)(ws +  64*MB);
  short* rot   = (short*)(ws +  64*MB);
  short* hsh   = (short*)(ws +  80*MB);
  short* nonab = (short*)(ws +  80*MB);
  short* abel  = (short*)(ws + 144*MB);
  short* eo    = (short*)(ws + 160*MB);
  short* MbT   = (short*)(ws + 192*MB);
  // small
  int*   counts   = (int*)  (ws + 194*MB);
  int*   ebase    = (int*)  (ws + 194*MB + 1024);
  int*   blockhist= (int*)  (ws + 194*MB + 2048);
  int*   blockoff = (int*)  (ws + 194*MB + 4096);
  int*   e0a   = (int*)  (ws + 194*MB +  64*1024);
  int*   e1a   = (int*)  (ws + 194*MB +  96*1024);
  float* w0a   = (float*)(ws + 194*MB + 128*1024);
  float* w1a   = (float*)(ws + 194*MB + 160*1024);
  int*   ctok  = (int*)  (ws + 194*MB + 192*1024);
  float* cw    = (float*)(ws + 194*MB + 256*1024);
  int*   t2r   = (int*)  (ws + 194*MB + 320*1024);

  // ---- stage a: M = expm(g0)..expm(g3), order-6 Taylor (commuting split)
  transpose_f32_to_bf16<<<dim3(32, 32, 4), 256, 0, stream>>>(gens, GbT, DIM, DIM, MELT, MELT, Gb, MELT);
  { // G2 = G*G (z=4)
    GemmArgs ga{}; ga.A = Gb; ga.BT = GbT; ga.sA = MELT; ga.sBT = MELT;
    ga.Cb = G2b; ga.sCb = MELT; ga.alpha = 1.f;
    ga.M = DIM; ga.N = DIM; ga.K = DIM; ga.lda = DIM; ga.ldb = DIM; ga.ldc = DIM;
    gemm_kernel<2,2><<<dim3(16, 16, 4), 256, 0, stream>>>(ga);
  }
  { // G3 = G2*G (z=4), keep row-major + transposed
    GemmArgs ga{}; ga.A = G2b; ga.BT = GbT; ga.sA = MELT; ga.sBT = MELT;
    ga.Cb = G3b; ga.sCb = MELT; ga.CbT = G3bT; ga.sCbT = MELT; ga.ldcbt = DIM;
    ga.alpha = 1.f;
    ga.M = DIM; ga.N = DIM; ga.K = DIM; ga.lda = DIM; ga.ldb = DIM; ga.ldc = DIM;
    gemm_kernel<2,2><<<dim3(16, 16, 4), 256, 0, stream>>>(ga);
  }
  poly6_kernel<<<4*MELT/256, 256, 0, stream>>>(gens, G2b, G3b, Racc, Sb);
  { // R = Racc + S*G3 (terms 4..6), fused: emit Rb (bf16) + RbT4 (transposed)
    GemmArgs ga{}; ga.A = Sb; ga.BT = G3bT; ga.sA = MELT; ga.sBT = MELT;
    ga.Racc = Racc; ga.sR = MELT;
    ga.Cb = Rb; ga.sCb = MELT;
    ga.CbT = RbT4; ga.sCbT = MELT; ga.ldcbt = DIM;
    ga.alpha = 1.f;
    ga.M = DIM; ga.N = DIM; ga.K = DIM; ga.lda = DIM; ga.ldb = DIM; ga.ldc = DIM;
    gemm_kernel<2,2><<<dim3(16, 16, 4), 256, 0, stream>>>(ga);
  }
  { // z=0: M01 = R0*R1 ; z=1: M23 = R2*R3   (BT slots: z=0->R1^T, z=1->R3^T)
    GemmArgs ga{}; ga.A = Rb; ga.BT = RbT4 + MELT; ga.sA = 2*MELT; ga.sBT = 2*MELT;
    ga.Cb = Mpair; ga.sCb = MELT; ga.CbT = MpairT; ga.sCbT = MELT; ga.ldcbt = DIM;
    ga.alpha = 1.f;
    ga.M = DIM; ga.N = DIM; ga.K = DIM; ga.lda = DIM; ga.ldb = DIM; ga.ldc = DIM;
    gemm_kernel<2,2><<<dim3(16, 16, 2), 256, 0, stream>>>(ga);
  }
  { // M = M01*M23, stored transposed
    GemmArgs ga{}; ga.A = Mpair; ga.BT = MpairT + MELT;
    ga.CbT = MbT; ga.ldcbt = DIM; ga.alpha = 1.f;
    ga.M = DIM; ga.N = DIM; ga.K = DIM; ga.lda = DIM; ga.ldb = DIM; ga.ldc = DIM;
    gemm_kernel<2,2><<<dim3(16, 16, 1), 256, 0, stream>>>(ga);
  }

  // ---- stage b: weight conversions (f32 -> bf16 [N,K])
  transpose_f32_to_bf16<<<dim3(A4D/32, DIM/32, 1), 256, 0, stream>>>(aw1, aw1bT, DIM, A4D, 0, 0, nullptr, 0);
  transpose_f32_to_bf16<<<dim3(DIM/32, A4D/32, 1), 256, 0, stream>>>(aw2, aw2bT, A4D, DIM, 0, 0, nullptr, 0);
  transpose_f32_to_bf16<<<dim3(HDIM/32, DIM/32, NE), 256, 0, stream>>>(ew1, ew1bT, DIM, HDIM, (long)DIM*HDIM, (long)DIM*HDIM, nullptr, 0);
  transpose_f32_to_bf16<<<dim3(DIM/32, HDIM/32, NE), 256, 0, stream>>>(ew2, ew2bT, HDIM, DIM, (long)DIM*HDIM, (long)DIM*HDIM, nullptr, 0);

  // ---- stage c: LayerNorm + routing, atomic-free compaction
  ln_route_kernel<<<T_TOK, 256, 0, stream>>>(x, ln_g, ln_b, gate_w, gate_b,
                                             xn_bf, e0a, e1a, w0a, w1a);
  hist_kernel<<<NBLK_R, 256, 0, stream>>>(e0a, e1a, blockhist);
  prefix2_kernel<<<1, 64, 0, stream>>>(blockhist, ebase, counts, blockoff);
  scatter2_kernel<<<NBLK_R, 256, 0, stream>>>(e0a, e1a, w0a, w1a, blockoff, ctok, cw, t2r);

  // ---- stage d: abel branch
  {
    GemmArgs ga{}; ga.A = xn_bf; ga.BT = aw1bT; ga.Cb = hsh;
    ga.bias = ab1; ga.alpha = 1.f; ga.do_gelu = 1;
    ga.M = T_TOK; ga.N = A4D; ga.K = DIM; ga.lda = DIM; ga.ldb = DIM; ga.ldc = A4D;
    gemm_sq256<<<dim3(A4D/256, T_TOK/256, 1), 1024, 0, stream>>>(ga);
  }
  {
    GemmArgs ga{}; ga.A = hsh; ga.BT = aw2bT; ga.Cb = abel;
    ga.bias = ab2; ga.alpha = 1.f;
    ga.M = T_TOK; ga.N = DIM; ga.K = A4D; ga.lda = A4D; ga.ldb = A4D; ga.ldc = DIM;
    gemm_kernel<4,4><<<dim3(DIM/128, T_TOK/128, 1), 256, 0, stream>>>(ga);
  }

  // ---- experts (gathered top-2)
  {
    GemmArgs ga{}; ga.mode = 1; ga.A = xn_bf; ga.BT = ew1bT; ga.sBT = (long)HDIM*DIM;
    ga.Cb = hsh; ga.bias = eb1; ga.sBias = HDIM; ga.alpha = 1.f; ga.do_gelu = 1;
    ga.toklist = ctok; ga.ebase = ebase; ga.ecount = counts;
    ga.M = T_TOK; ga.N = HDIM; ga.K = DIM; ga.lda = DIM; ga.ldb = DIM; ga.ldc = HDIM;
    gemm_sq256<<<dim3(HDIM/256, T_TOK/256, NE), 1024, 0, stream>>>(ga);
  }
  {
    GemmArgs ga{}; ga.mode = 2; ga.A = hsh; ga.BT = ew2bT; ga.sBT = (long)DIM*HDIM;
    ga.Cb = eo; ga.bias = eb2; ga.sBias = DIM; ga.rowscale = cw; ga.alpha = 1.f;
    ga.ebase = ebase; ga.ecount = counts;
    ga.M = T_TOK; ga.N = DIM; ga.K = HDIM; ga.lda = HDIM; ga.ldb = HDIM; ga.ldc = DIM;
    gemm_kernel<4,4><<<dim3(DIM/128, T_TOK/128, NE), 256, 0, stream>>>(ga);
  }
  combine_kernel<<<T_TOK, 256, 0, stream>>>(eo, t2r, nonab);

  // ---- rot = nonabel @ M
  {
    GemmArgs ga{}; ga.A = nonab; ga.BT = MbT; ga.Cb = rot; ga.alpha = 1.f;
    ga.M = T_TOK; ga.N = DIM; ga.K = DIM; ga.lda = DIM; ga.ldb = DIM; ga.ldc = DIM;
    gemm_kernel<4,4><<<dim3(DIM/128, T_TOK/128, 1), 256, 0, stream>>>(ga);
  }

  final_kernel<<<T_TOK, 256, 0, stream>>>(x, abel, rot, gc_w, gc_b, out);
}